// Round 5
// baseline (360.956 us; speedup 1.0000x reference)
//
#include <hip/hip_runtime.h>
#include <math.h>

// ---- problem constants -------------------------------------------------
constexpr int B_    = 4;
constexpr int S_    = 2048;
constexpr int F_    = 512;     // IN_FEATURES
constexpr int H_    = 8;       // NUM_HEADS
constexpr int D_    = 32;      // HEAD_DIM
constexpr int HID_  = 256;     // H_*D_
constexpr int NA_   = 16;      // NUM_ACTIONS
constexpr int ROWS_ = B_ * S_; // 8192
constexpr int CHUNK_= 32;      // steps per scan chunk
constexpr int NC_   = S_ / CHUNK_;  // 64 chunks
constexpr int T_    = 16;      // timesteps staged per LDS tile
constexpr int NT_   = CHUNK_ / T_;  // 2 tiles per chunk
constexpr int BH_   = B_ * H_;      // 32

typedef __attribute__((ext_vector_type(8))) short short8;
typedef __attribute__((ext_vector_type(4))) float f32x4;
typedef unsigned short u16;

__device__ __forceinline__ float sigmoidf_(float x) { return 1.0f / (1.0f + expf(-x)); }

// fp32 -> bf16 (RNE) and back, plus hi/lo split (a ~= hi + lo, err ~2^-17 rel)
__device__ __forceinline__ u16 f2bf(float f) {
    unsigned u = __float_as_uint(f);
    return (u16)((u + 0x7FFF + ((u >> 16) & 1)) >> 16);
}
__device__ __forceinline__ float bf2f(u16 h) {
    return __uint_as_float(((unsigned)h) << 16);
}
__device__ __forceinline__ void bfsplit(float x, u16& hi, u16& lo) {
    hi = f2bf(x);
    lo = f2bf(x - bf2f(hi));
}

// XOR swizzle within a 64-byte LDS row
__device__ __forceinline__ unsigned swz(unsigned r, unsigned cbyte) {
    return cbyte ^ (((r >> 1) & 3) << 4);
}

// ---- K0a: convert x (f32) -> xh, xl bf16 (row-major 8192x512) ----------
__global__ __launch_bounds__(256) void conv_x_kernel(
    const float* __restrict__ x, u16* __restrict__ xh, u16* __restrict__ xl)
{
    const int idx = blockIdx.x * 256 + threadIdx.x;       // one float4 each
    const float4 v = ((const float4*)x)[idx];
    ushort4 h, l;
    bfsplit(v.x, h.x, l.x); bfsplit(v.y, h.y, l.y);
    bfsplit(v.z, h.z, l.z); bfsplit(v.w, h.w, l.w);
    ((ushort4*)xh)[idx] = h;
    ((ushort4*)xl)[idx] = l;
}

// ---- K0b: transpose + convert weights to [N][K] bf16 hi/lo -------------
__global__ __launch_bounds__(256) void conv_w_kernel(
    const float* __restrict__ Wq, const float* __restrict__ Wk,
    const float* __restrict__ Wv, const float* __restrict__ Wout,
    u16* __restrict__ wth, u16* __restrict__ wtl,
    u16* __restrict__ woth, u16* __restrict__ wotl)
{
    const int z = blockIdx.z;
    const float* src; u16 *dh, *dl; int R, C;
    if (z < 3) {
        src = (z == 0) ? Wq : (z == 1) ? Wk : Wv;
        R = 512; C = 256;
        dh = wth + (size_t)z * 256 * 512; dl = wtl + (size_t)z * 256 * 512;
    } else {
        src = Wout; R = 256; C = 512; dh = woth; dl = wotl;
    }
    const int r0 = blockIdx.x * 32, c0 = blockIdx.y * 32;
    if (r0 >= R || c0 >= C) return;
    __shared__ float tile[32][33];
    const int tx = threadIdx.x & 31, ty = threadIdx.x >> 5;   // 32x8
    #pragma unroll
    for (int i = 0; i < 4; i++)
        tile[ty + i * 8][tx] = src[(size_t)(r0 + ty + i * 8) * C + c0 + tx];
    __syncthreads();
    #pragma unroll
    for (int i = 0; i < 4; i++) {
        const float v = tile[tx][ty + i * 8];
        const size_t o = (size_t)(c0 + ty + i * 8) * R + r0 + tx;
        u16 h, l; bfsplit(v, h, l);
        dh[o] = h; dl[o] = l;
    }
}

// ---- K0c: pack Wbeta|Walpha -> wba [16][512] bf16 hi/lo (rows 16-63 unused)
__global__ __launch_bounds__(256) void conv_ba_kernel(
    const float* __restrict__ Wb, const float* __restrict__ Wa,
    u16* __restrict__ wbah, u16* __restrict__ wbal)
{
    const int idx = blockIdx.x * 256 + threadIdx.x;   // 16*512 total
    const int j = idx >> 9, k = idx & 511;
    const float v = (j < 8) ? Wb[(size_t)k * 8 + j] : Wa[(size_t)k * 8 + (j - 8)];
    u16 h, l; bfsplit(v, h, l);
    wbah[(size_t)j * 512 + k] = h;
    wbal[(size_t)j * 512 + k] = l;
}

// ---- K1a: MFMA GEMM  C[8192xN] = A[8192xK] @ Bt[NxK]^T  (bf16x3) -------
__global__ __launch_bounds__(128) void mfma_gemm_kernel(
    const u16* __restrict__ Ah, const u16* __restrict__ Al,
    const u16* __restrict__ Bth, const u16* __restrict__ Btl,
    float* __restrict__ Cbase, int K, int N,
    int btStride, int cStride, const float* __restrict__ bias)
{
    const u16* bh_p = Bth + (size_t)blockIdx.z * btStride;
    const u16* bl_p = Btl + (size_t)blockIdx.z * btStride;
    float* C = Cbase + (size_t)blockIdx.z * cStride;

    __shared__ u16 lAh[128 * 32], lAl[128 * 32];   // 8 KB each
    __shared__ u16 lBh[64 * 32],  lBl[64 * 32];    // 4 KB each

    const int t    = threadIdx.x;
    const int wave = t >> 6;
    const int lane = t & 63;
    const int lr   = lane & 15;        // row/col within fragment
    const int lk   = lane >> 4;        // k-quad (0..3)
    const int row0 = blockIdx.x * 128;
    const int col0 = blockIdx.y * 64;

    f32x4 acc[4][4];
    #pragma unroll
    for (int i = 0; i < 4; i++)
        #pragma unroll
        for (int j = 0; j < 4; j++) acc[i][j] = (f32x4){0.f, 0.f, 0.f, 0.f};

    for (int k0 = 0; k0 < K; k0 += 32) {
        #pragma unroll
        for (int u = 0; u < 4; u++) {
            const int slot = t + u * 128;
            const int r = slot >> 2, cq = slot & 3;
            const size_t g = (size_t)(row0 + r) * K + k0 + cq * 8;
            const unsigned bo = r * 64 + swz(r, cq * 16);
            *(uint4*)((char*)lAh + bo) = *(const uint4*)(Ah + g);
            *(uint4*)((char*)lAl + bo) = *(const uint4*)(Al + g);
        }
        #pragma unroll
        for (int u = 0; u < 2; u++) {
            const int slot = t + u * 128;
            const int r = slot >> 2, cq = slot & 3;
            const size_t g = (size_t)(col0 + r) * K + k0 + cq * 8;
            const unsigned bo = r * 64 + swz(r, cq * 16);
            *(uint4*)((char*)lBh + bo) = *(const uint4*)(bh_p + g);
            *(uint4*)((char*)lBl + bo) = *(const uint4*)(bl_p + g);
        }
        __syncthreads();

        short8 ah[4], al[4];
        #pragma unroll
        for (int tm = 0; tm < 4; tm++) {
            const int r = wave * 64 + tm * 16 + lr;
            const unsigned bo = r * 64 + swz(r, lk * 16);
            ah[tm] = *(const short8*)((const char*)lAh + bo);
            al[tm] = *(const short8*)((const char*)lAl + bo);
        }
        #pragma unroll
        for (int tn = 0; tn < 4; tn++) {
            const int r = tn * 16 + lr;
            const unsigned bo = r * 64 + swz(r, lk * 16);
            const short8 bh = *(const short8*)((const char*)lBh + bo);
            const short8 bl = *(const short8*)((const char*)lBl + bo);
            #pragma unroll
            for (int tm = 0; tm < 4; tm++) {
                acc[tm][tn] = __builtin_amdgcn_mfma_f32_16x16x32_bf16(
                    ah[tm], bh, acc[tm][tn], 0, 0, 0);
                acc[tm][tn] = __builtin_amdgcn_mfma_f32_16x16x32_bf16(
                    ah[tm], bl, acc[tm][tn], 0, 0, 0);
                acc[tm][tn] = __builtin_amdgcn_mfma_f32_16x16x32_bf16(
                    al[tm], bh, acc[tm][tn], 0, 0, 0);
            }
        }
        __syncthreads();
    }

    #pragma unroll
    for (int tm = 0; tm < 4; tm++) {
        #pragma unroll
        for (int tn = 0; tn < 4; tn++) {
            const int col = col0 + tn * 16 + lr;
            const float b = bias ? bias[col] : 0.0f;
            #pragma unroll
            for (int v = 0; v < 4; v++) {
                const int row = row0 + wave * 64 + tm * 16 + lk * 4 + v;
                C[(size_t)row * N + col] = acc[tm][tn][v] + b;
            }
        }
    }
}

// ---- K1c: action projections (K=16) ku/vu/gamma ------------------------
__global__ __launch_bounds__(256) void gemm_act_kernel(
    const float* __restrict__ act, const float* __restrict__ Wku,
    const float* __restrict__ Wvu, const float* __restrict__ Wg,
    float* __restrict__ ku, float* __restrict__ vu, float* __restrict__ bg)
{
    int o = blockIdx.x * 256 + threadIdx.x;
    const int total = ROWS_ * 520;           // 256 + 256 + 8
    if (o >= total) return;
    int row = o / 520;
    int col = o - row * 520;
    const float* a = act + (size_t)row * NA_;
    float acc = 0.0f;
    if (col < 256) {
        #pragma unroll
        for (int kk = 0; kk < NA_; kk++) acc += a[kk] * Wku[kk * HID_ + col];
        ku[(size_t)row * HID_ + col] = acc;
    } else if (col < 512) {
        int c = col - 256;
        #pragma unroll
        for (int kk = 0; kk < NA_; kk++) acc += a[kk] * Wvu[kk * HID_ + c];
        vu[(size_t)row * HID_ + c] = acc;
    } else {
        int c = col - 512;
        #pragma unroll
        for (int kk = 0; kk < NA_; kk++) acc += a[kk] * Wg[kk * H_ + c];
        bg[(size_t)row * H_ + c] = sigmoidf_(acc);
    }
}

// ---- K2: silu + l2norm (per 32-elem head group) for q, k, ku, in place -
__global__ __launch_bounds__(256) void silu_norm_kernel(
    float* __restrict__ q, float* __restrict__ k, float* __restrict__ ku)
{
    const int t = threadIdx.x;
    const int d = t & 31;
    const size_t g = (size_t)blockIdx.x * 8 + (t >> 5);   // head-group id
    const size_t idx = g * 32 + d;
    float* bufs[3] = { q, k, ku };
    #pragma unroll
    for (int a = 0; a < 3; a++) {
        float x = bufs[a][idx];
        float v = x * (1.0f / (1.0f + expf(-x)));
        float ss = v * v;
        ss += __shfl_xor(ss, 1);  ss += __shfl_xor(ss, 2);  ss += __shfl_xor(ss, 4);
        ss += __shfl_xor(ss, 8);  ss += __shfl_xor(ss, 16);
        bufs[a][idx] = v * rsqrtf(ss + 1e-6f);
    }
}

// ---- K3a: per-chunk (cumA, cumB) via rank-1 recurrences ----------------
// 256 threads per chunk: row i = t>>3 (0..31), 4 cols per thread.
// CHUNK_=32 -> 2048 blocks = 8 blocks/CU = 32 waves/CU (occupancy cap).
__global__ __launch_bounds__(256) void scan_pass1(
    const float* __restrict__ kbuf, const float* __restrict__ vbuf,
    const float* __restrict__ kubuf, const float* __restrict__ vubuf,
    const float* __restrict__ bab, const float* __restrict__ gammab,
    const float* __restrict__ mask,
    float* __restrict__ cumA, float* __restrict__ cumB)
{
    const int bh = blockIdx.x;     // 0..31
    const int c  = blockIdx.y;     // 0..NC_-1
    const int b  = bh >> 3, h = bh & 7;
    const int t  = threadIdx.x;
    const int i  = t >> 3;         // state row
    const int j0 = (t & 7) * 4;    // 4 state cols
    __shared__ float lk [T_][32];
    __shared__ float lv [T_][32];
    __shared__ float lku[T_][32];
    __shared__ float lvu[T_][32];
    __shared__ float lsc[T_][4];   // 0:beta 1:alpha*(1-mask) 2:gamma

    float M[4], Cc[4];
    #pragma unroll
    for (int jj = 0; jj < 4; jj++) { M[jj] = (i == j0 + jj) ? 1.0f : 0.0f; Cc[jj] = 0.0f; }

    const float* g0 = (t < 128) ? kbuf  : vbuf;
    const float* g1 = (t < 128) ? kubuf : vubuf;
    const int sr = (t >> 3) & 15, sq = t & 7;

    auto stage = [&](int tile, float4& n0, float4& n1, float& sc) {
        const int row_base = b * S_ + c * CHUNK_ + tile * T_;
        const size_t gb = (size_t)(row_base + sr) * HID_ + h * D_ + sq * 4;
        n0 = *(const float4*)(g0 + gb);
        n1 = *(const float4*)(g1 + gb);
        const int r = t & 15;
        const int rowi = row_base + r;
        if (t < 16)                     sc = sigmoidf_(bab[(size_t)rowi * 64 + h]);
        else if (t >= 64 && t < 80)     sc = sigmoidf_(bab[(size_t)rowi * 64 + 8 + h]) * (1.0f - mask[rowi]);
        else if (t >= 128 && t < 144)   sc = gammab[(size_t)rowi * H_ + h];
    };
    auto commit = [&](float4 n0, float4 n1, float sc) {
        if (t < 128) {
            *(float4*)&lk [sr][sq*4] = n0;
            *(float4*)&lku[sr][sq*4] = n1;
        } else {
            *(float4*)&lv [sr][sq*4] = n0;
            *(float4*)&lvu[sr][sq*4] = n1;
        }
        const int r = t & 15;
        if (t < 16)                     lsc[r][0] = sc;
        else if (t >= 64 && t < 80)     lsc[r][1] = sc;
        else if (t >= 128 && t < 144)   lsc[r][2] = sc;
    };

    float4 p0, p1; float psc = 0.0f;
    stage(0, p0, p1, psc);

    for (int tile = 0; tile < NT_; ++tile) {
        commit(p0, p1, psc);
        __syncthreads();
        float4 n0, n1; float nsc = 0.0f;
        if (tile + 1 < NT_) stage(tile + 1, n0, n1, nsc);

        #pragma unroll
        for (int sl = 0; sl < T_; sl++) {
            const float vi  = lv [sl][i];
            const float vui = lvu[sl][i];
            const float bet = lsc[sl][0];
            const float a   = lsc[sl][1];
            const float bgm = lsc[sl][2];
            float kj[4], kuj[4];
            *(float4*)kj  = *(const float4*)&lk [sl][j0];
            *(float4*)kuj = *(const float4*)&lku[sl][j0];
            float pd = 0.0f, mk = 0.0f, ck = 0.0f;
            #pragma unroll
            for (int jj = 0; jj < 4; jj++) {
                pd += kuj[jj] * kj[jj];
                mk += M[jj]   * kj[jj];
                ck += Cc[jj]  * kj[jj];
            }
            pd += __shfl_xor(pd, 1); pd += __shfl_xor(pd, 2); pd += __shfl_xor(pd, 4);
            mk += __shfl_xor(mk, 1); mk += __shfl_xor(mk, 2); mk += __shfl_xor(mk, 4);
            ck += __shfl_xor(ck, 1); ck += __shfl_xor(ck, 2); ck += __shfl_xor(ck, 4);
            const float abk_m   = a * bet * mk;
            const float ck_coef = bet * vi - a * bet * ck;
            const float wu      = bgm * vui;
            const float bduk    = bet * pd;
            #pragma unroll
            for (int jj = 0; jj < 4; jj++) {
                const float kv = kj[jj];
                const float w  = kuj[jj] - bduk * kv;         // (ku^T @ delta)[j]
                M[jj]  = a * M[jj]  - abk_m   * kv;           // M @ decay
                Cc[jj] = a * Cc[jj] + ck_coef * kv + wu * w;  // C @ decay + update
            }
        }
        __syncthreads();
        p0 = n0; p1 = n1; psc = nsc;
    }
    const size_t ofs = ((size_t)(bh * NC_ + c)) * 1024 + (size_t)i * 32 + j0;
    *(float4*)(cumA + ofs) = make_float4(M[0],  M[1],  M[2],  M[3]);
    *(float4*)(cumB + ofs) = make_float4(Cc[0], Cc[1], Cc[2], Cc[3]);
}

// ---- K3b: sequential chunk composition; Sstart MAY ALIAS cumA ----------
// (iter c writes Sstart[c] only after cumA[c] was consumed; prefetch reads
//  cumA[c+1] before iter c+1 overwrites it -- safe.)
__global__ __launch_bounds__(1024) void scan_pass2(
    const float* __restrict__ carry, const float* __restrict__ cumA,
    const float* __restrict__ cumB, float* __restrict__ Sstart,
    float* __restrict__ carry_out)
{
    const int bh = blockIdx.x;
    const int t  = threadIdx.x;
    const int i  = t >> 5;
    const int j  = t & 31;
    __shared__ float Ssh[32][33];
    __shared__ float Ash[32][33];
    const size_t idx = (size_t)i * 32 + j;
    float Sv = carry[(size_t)bh * 1024 + idx];

    float Anext = cumA[((size_t)(bh * NC_)) * 1024 + idx];
    float Bnext = cumB[((size_t)(bh * NC_)) * 1024 + idx];
    for (int c = 0; c < NC_; c++) {
        const size_t ofs = ((size_t)(bh * NC_ + c)) * 1024;
        Ssh[i][j] = Sv;
        Ash[i][j] = Anext;
        const float Bcur = Bnext;
        __syncthreads();
        Sstart[ofs + idx] = Sv;
        if (c + 1 < NC_) {                 // issue next chunk's loads early
            const size_t ofs2 = ofs + 1024;
            Anext = cumA[ofs2 + idx];
            Bnext = cumB[ofs2 + idx];
        }
        float acc = Bcur;
        #pragma unroll 8
        for (int m = 0; m < 32; m++) acc += Ssh[i][m] * Ash[m][j];
        __syncthreads();
        Sv = acc;
    }
    carry_out[(size_t)bh * 1024 + idx] = Sv;
}

// ---- K3c: replay each chunk from Sstart, emit out = S_new . q ----------
__global__ __launch_bounds__(256) void scan_pass3(
    const float* __restrict__ qbuf, const float* __restrict__ kbuf,
    const float* __restrict__ vbuf, const float* __restrict__ kubuf,
    const float* __restrict__ vubuf, const float* __restrict__ bab,
    const float* __restrict__ gammab, const float* __restrict__ mask,
    const float* __restrict__ Sstart, float* __restrict__ outpre)
{
    const int bh = blockIdx.x, c = blockIdx.y;
    const int b  = bh >> 3, h = bh & 7;
    const int t  = threadIdx.x;
    const int i  = t >> 3;
    const int j0 = (t & 7) * 4;
    __shared__ float lk [T_][32];
    __shared__ float lq [T_][32];
    __shared__ float lv [T_][32];
    __shared__ float lku[T_][32];
    __shared__ float lvu[T_][32];
    __shared__ float lsc[T_][4];

    float Sv[4];
    const size_t sofs = ((size_t)(bh * NC_ + c)) * 1024 + (size_t)i * 32 + j0;
    {
        float4 s4 = *(const float4*)(Sstart + sofs);
        Sv[0] = s4.x; Sv[1] = s4.y; Sv[2] = s4.z; Sv[3] = s4.w;
    }

    const float* g0 = (t < 128) ? kbuf  : vbuf;
    const float* g1 = (t < 128) ? kubuf : vubuf;
    const int sr = (t >> 3) & 15, sq = t & 7;

    auto stage = [&](int tile, float4& n0, float4& n1, float4& n2, float& sc) {
        const int row_base = b * S_ + c * CHUNK_ + tile * T_;
        const size_t gb = (size_t)(row_base + sr) * HID_ + h * D_ + sq * 4;
        n0 = *(const float4*)(g0 + gb);
        n1 = *(const float4*)(g1 + gb);
        if (t < 128) n2 = *(const float4*)(qbuf + gb);
        const int r = t & 15;
        const int rowi = row_base + r;
        if (t < 16)                     sc = sigmoidf_(bab[(size_t)rowi * 64 + h]);
        else if (t >= 64 && t < 80)     sc = sigmoidf_(bab[(size_t)rowi * 64 + 8 + h]) * (1.0f - mask[rowi]);
        else if (t >= 128 && t < 144)   sc = gammab[(size_t)rowi * H_ + h];
    };
    auto commit = [&](float4 n0, float4 n1, float4 n2, float sc) {
        if (t < 128) {
            *(float4*)&lk [sr][sq*4] = n0;
            *(float4*)&lku[sr][sq*4] = n1;
            *(float4*)&lq [sr][sq*4] = n2;
        } else {
            *(float4*)&lv [sr][sq*4] = n0;
            *(float4*)&lvu[sr][sq*4] = n1;
        }
        const int r = t & 15;
        if (t < 16)                     lsc[r][0] = sc;
        else if (t >= 64 && t < 80)     lsc[r][1] = sc;
        else if (t >= 128 && t < 144)   lsc[r][2] = sc;
    };

    float4 p0, p1, p2; float psc = 0.0f;
    stage(0, p0, p1, p2, psc);

    for (int tile = 0; tile < NT_; ++tile) {
        commit(p0, p1, p2, psc);
        __syncthreads();
        float4 n0, n1, n2; float nsc = 0.0f;
        if (tile + 1 < NT_) stage(tile + 1, n0, n1, n2, nsc);

        const int row_base = b * S_ + c * CHUNK_ + tile * T_;
        #pragma unroll
        for (int sl = 0; sl < T_; sl++) {
            const float vi  = lv [sl][i];
            const float vui = lvu[sl][i];
            const float bet = lsc[sl][0];
            const float a   = lsc[sl][1];
            const float bgm = lsc[sl][2];
            float kj[4], kuj[4], qj[4];
            *(float4*)kj  = *(const float4*)&lk [sl][j0];
            *(float4*)kuj = *(const float4*)&lku[sl][j0];
            *(float4*)qj  = *(const float4*)&lq [sl][j0];
            float pd = 0.0f, sk = 0.0f;
            #pragma unroll
            for (int jj = 0; jj < 4; jj++) {
                pd += kuj[jj] * kj[jj];
                sk += Sv[jj]  * kj[jj];
            }
            pd += __shfl_xor(pd, 1); pd += __shfl_xor(pd, 2); pd += __shfl_xor(pd, 4);
            sk += __shfl_xor(sk, 1); sk += __shfl_xor(sk, 2); sk += __shfl_xor(sk, 4);
            const float coef_k = bet * vi - a * bet * sk;
            const float wu     = bgm * vui;
            const float bduk   = bet * pd;
            float op = 0.0f;
            #pragma unroll
            for (int jj = 0; jj < 4; jj++) {
                const float kv = kj[jj];
                const float w  = kuj[jj] - bduk * kv;
                Sv[jj] = a * Sv[jj] + coef_k * kv + wu * w;
                op += Sv[jj] * qj[jj];
            }
            op += __shfl_xor(op, 1); op += __shfl_xor(op, 2); op += __shfl_xor(op, 4);
            if ((t & 7) == 0)
                outpre[(size_t)(row_base + sl) * HID_ + h * D_ + i] = op;
        }
        __syncthreads();
        p0 = n0; p1 = n1; p2 = n2; psc = nsc;
    }
}

// ---- K4a: RMS norm + rms_scale -> bf16 hi/lo (one wave per row) --------
__global__ __launch_bounds__(256) void rms_conv_kernel(
    const float* __restrict__ outpre, const float* __restrict__ rms_scale,
    u16* __restrict__ onh, u16* __restrict__ onl)
{
    const int t = threadIdx.x;
    const int lane = t & 63;
    const int row = blockIdx.x * 4 + (t >> 6);
    const float4 v = ((const float4*)(outpre + (size_t)row * HID_))[lane];
    float ss = v.x*v.x + v.y*v.y + v.z*v.z + v.w*v.w;
    ss += __shfl_xor(ss, 1);  ss += __shfl_xor(ss, 2);  ss += __shfl_xor(ss, 4);
    ss += __shfl_xor(ss, 8);  ss += __shfl_xor(ss, 16); ss += __shfl_xor(ss, 32);
    const float rinv = rsqrtf(ss * (1.0f / HID_) + 1e-6f);
    const float4 sc = ((const float4*)rms_scale)[lane];
    ushort4 h, l;
    bfsplit(v.x * rinv * sc.x, h.x, l.x);
    bfsplit(v.y * rinv * sc.y, h.y, l.y);
    bfsplit(v.z * rinv * sc.z, h.z, l.z);
    bfsplit(v.w * rinv * sc.w, h.w, l.w);
    ((ushort4*)(onh + (size_t)row * HID_))[lane] = h;
    ((ushort4*)(onl + (size_t)row * HID_))[lane] = l;
}

// ---- launch ------------------------------------------------------------
extern "C" void kernel_launch(void* const* d_in, const int* in_sizes, int n_in,
                              void* d_out, int out_size, void* d_ws, size_t ws_size,
                              hipStream_t stream)
{
    const float* x      = (const float*)d_in[0];
    const float* action = (const float*)d_in[1];
    const float* mask   = (const float*)d_in[2];
    const float* carry  = (const float*)d_in[3];
    const float* Wq     = (const float*)d_in[4];
    const float* Wk     = (const float*)d_in[5];
    const float* Wv     = (const float*)d_in[6];
    const float* Wbeta  = (const float*)d_in[7];
    const float* Walpha = (const float*)d_in[8];
    const float* Wku    = (const float*)d_in[9];
    const float* Wvu    = (const float*)d_in[10];
    const float* Wgamma = (const float*)d_in[11];
    const float* rms_s  = (const float*)d_in[12];
    const float* Wout   = (const float*)d_in[13];
    const float* bout   = (const float*)d_in[14];

    float* carry_out = (float*)d_out;                       // B*H*D*D = 32768
    float* y         = (float*)d_out + (size_t)BH_ * D_ * D_;

    float* ws = (float*)d_ws;
    float* qb     = ws; ws += (size_t)ROWS_ * HID_;
    float* kb     = ws; ws += (size_t)ROWS_ * HID_;
    float* vb     = ws; ws += (size_t)ROWS_ * HID_;
    float* kub    = ws; ws += (size_t)ROWS_ * HID_;
    float* vub    = ws; ws += (size_t)ROWS_ * HID_;
    float* bab    = ws; ws += (size_t)ROWS_ * 64;          // beta|alpha logits
    float* gammab = ws; ws += (size_t)ROWS_ * H_;
    float* cumA   = ws; ws += (size_t)BH_ * NC_ * D_ * D_; // Sstart aliases this
    float* cumB   = ws; ws += (size_t)BH_ * NC_ * D_ * D_;
    u16* xh       = (u16*)ws;                               // outpre aliases xh/xl
    float* outpre = ws; ws += (size_t)ROWS_ * HID_;
    u16* xl       = (u16*)ws; ws += (size_t)ROWS_ * F_ / 2;
    u16* wth      = (u16*)ws; ws += (size_t)3 * HID_ * F_ / 2;
    u16* wtl      = (u16*)ws; ws += (size_t)3 * HID_ * F_ / 2;
    u16* woth     = (u16*)ws; ws += (size_t)F_ * HID_ / 2;
    u16* wotl     = (u16*)ws; ws += (size_t)F_ * HID_ / 2;
    u16* wbah     = (u16*)ws; ws += (size_t)64 * F_ / 2;   // rows 16-63 unused
    u16* wbal     = (u16*)ws; ws += (size_t)64 * F_ / 2;
    float* Sst    = cumA;
    // onh/onl alias qb (free after scan_pass3; each 4 MB, qb is 8 MB)
    u16* onh = (u16*)qb;
    u16* onl = (u16*)qb + (size_t)ROWS_ * HID_;

    conv_x_kernel<<<dim3(ROWS_ * F_ / 4 / 256), 256, 0, stream>>>(x, xh, xl);
    conv_w_kernel<<<dim3(16, 16, 4), 256, 0, stream>>>(
        Wq, Wk, Wv, Wout, wth, wtl, woth, wotl);
    conv_ba_kernel<<<dim3(16 * F_ / 256), 256, 0, stream>>>(Wbeta, Walpha, wbah, wbal);
    mfma_gemm_kernel<<<dim3(ROWS_/128, HID_/64, 3), 128, 0, stream>>>(
        xh, xl, wth, wtl, qb, F_, HID_, HID_ * F_, ROWS_ * HID_, nullptr);
    mfma_gemm_kernel<<<dim3(ROWS_/128, 1, 1), 128, 0, stream>>>(
        xh, xl, wbah, wbal, bab, F_, 64, 0, 0, nullptr);
    gemm_act_kernel<<<dim3((ROWS_*520 + 255)/256), 256, 0, stream>>>(
        action, Wku, Wvu, Wgamma, kub, vub, gammab);
    silu_norm_kernel<<<dim3(ROWS_*H_/8), 256, 0, stream>>>(qb, kb, kub);
    scan_pass1<<<dim3(BH_, NC_), 256, 0, stream>>>(
        kb, vb, kub, vub, bab, gammab, mask, cumA, cumB);
    scan_pass2<<<dim3(BH_), 1024, 0, stream>>>(carry, cumA, cumB, Sst, carry_out);
    scan_pass3<<<dim3(BH_, NC_), 256, 0, stream>>>(
        qb, kb, vb, kub, vub, bab, gammab, mask, Sst, outpre);
    rms_conv_kernel<<<dim3(ROWS_/4), 256, 0, stream>>>(outpre, rms_s, onh, onl);
    mfma_gemm_kernel<<<dim3(ROWS_/128, F_/64, 1), 128, 0, stream>>>(
        onh, onl, woth, wotl, y, HID_, F_, 0, 0, bout);
}

// Round 7
// 309.378 us; speedup vs baseline: 1.1667x; 1.1667x over previous
//
#include <hip/hip_runtime.h>
#include <math.h>

// ---- problem constants -------------------------------------------------
constexpr int B_    = 4;
constexpr int S_    = 2048;
constexpr int F_    = 512;     // IN_FEATURES
constexpr int H_    = 8;       // NUM_HEADS
constexpr int D_    = 32;      // HEAD_DIM
constexpr int HID_  = 256;     // H_*D_
constexpr int NA_   = 16;      // NUM_ACTIONS
constexpr int ROWS_ = B_ * S_; // 8192
constexpr int CHUNK_= 32;      // steps per scan chunk
constexpr int NC_   = S_ / CHUNK_;  // 64 chunks
constexpr int T_    = 16;      // timesteps staged per LDS tile
constexpr int NT_   = CHUNK_ / T_;  // 2 tiles per chunk
constexpr int BH_   = B_ * H_;      // 32

typedef __attribute__((ext_vector_type(8))) short short8;
typedef __attribute__((ext_vector_type(4))) float f32x4;
typedef unsigned short u16;

__device__ __forceinline__ float sigmoidf_(float x) { return 1.0f / (1.0f + expf(-x)); }

// fp32 -> bf16 (RNE) and back, plus hi/lo split (a ~= hi + lo, err ~2^-17 rel)
__device__ __forceinline__ u16 f2bf(float f) {
    unsigned u = __float_as_uint(f);
    return (u16)((u + 0x7FFF + ((u >> 16) & 1)) >> 16);
}
__device__ __forceinline__ float bf2f(u16 h) {
    return __uint_as_float(((unsigned)h) << 16);
}
__device__ __forceinline__ void bfsplit(float x, u16& hi, u16& lo) {
    hi = f2bf(x);
    lo = f2bf(x - bf2f(hi));
}

// XOR swizzle within a 64-byte LDS row
__device__ __forceinline__ unsigned swz(unsigned r, unsigned cbyte) {
    return cbyte ^ (((r >> 1) & 3) << 4);
}

// ---- K0a: convert x (f32) -> xh, xl bf16 (row-major 8192x512) ----------
__global__ __launch_bounds__(256) void conv_x_kernel(
    const float* __restrict__ x, u16* __restrict__ xh, u16* __restrict__ xl)
{
    const int idx = blockIdx.x * 256 + threadIdx.x;       // one float4 each
    const float4 v = ((const float4*)x)[idx];
    ushort4 h, l;
    bfsplit(v.x, h.x, l.x); bfsplit(v.y, h.y, l.y);
    bfsplit(v.z, h.z, l.z); bfsplit(v.w, h.w, l.w);
    ((ushort4*)xh)[idx] = h;
    ((ushort4*)xl)[idx] = l;
}

// ---- K0b: transpose + convert weights to [N][K] bf16 hi/lo -------------
__global__ __launch_bounds__(256) void conv_w_kernel(
    const float* __restrict__ Wq, const float* __restrict__ Wk,
    const float* __restrict__ Wv, const float* __restrict__ Wout,
    u16* __restrict__ wth, u16* __restrict__ wtl,
    u16* __restrict__ woth, u16* __restrict__ wotl)
{
    const int z = blockIdx.z;
    const float* src; u16 *dh, *dl; int R, C;
    if (z < 3) {
        src = (z == 0) ? Wq : (z == 1) ? Wk : Wv;
        R = 512; C = 256;
        dh = wth + (size_t)z * 256 * 512; dl = wtl + (size_t)z * 256 * 512;
    } else {
        src = Wout; R = 256; C = 512; dh = woth; dl = wotl;
    }
    const int r0 = blockIdx.x * 32, c0 = blockIdx.y * 32;
    if (r0 >= R || c0 >= C) return;
    __shared__ float tile[32][33];
    const int tx = threadIdx.x & 31, ty = threadIdx.x >> 5;   // 32x8
    #pragma unroll
    for (int i = 0; i < 4; i++)
        tile[ty + i * 8][tx] = src[(size_t)(r0 + ty + i * 8) * C + c0 + tx];
    __syncthreads();
    #pragma unroll
    for (int i = 0; i < 4; i++) {
        const float v = tile[tx][ty + i * 8];
        const size_t o = (size_t)(c0 + ty + i * 8) * R + r0 + tx;
        u16 h, l; bfsplit(v, h, l);
        dh[o] = h; dl[o] = l;
    }
}

// ---- K0c: pack Wbeta|Walpha -> wba [16][512] bf16 hi/lo ----------------
__global__ __launch_bounds__(256) void conv_ba_kernel(
    const float* __restrict__ Wb, const float* __restrict__ Wa,
    u16* __restrict__ wbah, u16* __restrict__ wbal)
{
    const int idx = blockIdx.x * 256 + threadIdx.x;   // 16*512 total
    const int j = idx >> 9, k = idx & 511;
    const float v = (j < 8) ? Wb[(size_t)k * 8 + j] : Wa[(size_t)k * 8 + (j - 8)];
    u16 h, l; bfsplit(v, h, l);
    wbah[(size_t)j * 512 + k] = h;
    wbal[(size_t)j * 512 + k] = l;
}

// ---- K1a: MFMA GEMM  C[8192xN] = A[8192xK] @ Bt[NxK]^T  (bf16x3) -------
__global__ __launch_bounds__(128) void mfma_gemm_kernel(
    const u16* __restrict__ Ah, const u16* __restrict__ Al,
    const u16* __restrict__ Bth, const u16* __restrict__ Btl,
    float* __restrict__ Cbase, int K, int N,
    int btStride, int cStride, const float* __restrict__ bias)
{
    const u16* bh_p = Bth + (size_t)blockIdx.z * btStride;
    const u16* bl_p = Btl + (size_t)blockIdx.z * btStride;
    float* C = Cbase + (size_t)blockIdx.z * cStride;

    __shared__ u16 lAh[128 * 32], lAl[128 * 32];   // 8 KB each
    __shared__ u16 lBh[64 * 32],  lBl[64 * 32];    // 4 KB each

    const int t    = threadIdx.x;
    const int wave = t >> 6;
    const int lane = t & 63;
    const int lr   = lane & 15;        // row/col within fragment
    const int lk   = lane >> 4;        // k-quad (0..3)
    const int row0 = blockIdx.x * 128;
    const int col0 = blockIdx.y * 64;

    f32x4 acc[4][4];
    #pragma unroll
    for (int i = 0; i < 4; i++)
        #pragma unroll
        for (int j = 0; j < 4; j++) acc[i][j] = (f32x4){0.f, 0.f, 0.f, 0.f};

    for (int k0 = 0; k0 < K; k0 += 32) {
        #pragma unroll
        for (int u = 0; u < 4; u++) {
            const int slot = t + u * 128;
            const int r = slot >> 2, cq = slot & 3;
            const size_t g = (size_t)(row0 + r) * K + k0 + cq * 8;
            const unsigned bo = r * 64 + swz(r, cq * 16);
            *(uint4*)((char*)lAh + bo) = *(const uint4*)(Ah + g);
            *(uint4*)((char*)lAl + bo) = *(const uint4*)(Al + g);
        }
        #pragma unroll
        for (int u = 0; u < 2; u++) {
            const int slot = t + u * 128;
            const int r = slot >> 2, cq = slot & 3;
            const size_t g = (size_t)(col0 + r) * K + k0 + cq * 8;
            const unsigned bo = r * 64 + swz(r, cq * 16);
            *(uint4*)((char*)lBh + bo) = *(const uint4*)(bh_p + g);
            *(uint4*)((char*)lBl + bo) = *(const uint4*)(bl_p + g);
        }
        __syncthreads();

        short8 ah[4], al[4];
        #pragma unroll
        for (int tm = 0; tm < 4; tm++) {
            const int r = wave * 64 + tm * 16 + lr;
            const unsigned bo = r * 64 + swz(r, lk * 16);
            ah[tm] = *(const short8*)((const char*)lAh + bo);
            al[tm] = *(const short8*)((const char*)lAl + bo);
        }
        #pragma unroll
        for (int tn = 0; tn < 4; tn++) {
            const int r = tn * 16 + lr;
            const unsigned bo = r * 64 + swz(r, lk * 16);
            const short8 bh = *(const short8*)((const char*)lBh + bo);
            const short8 bl = *(const short8*)((const char*)lBl + bo);
            #pragma unroll
            for (int tm = 0; tm < 4; tm++) {
                acc[tm][tn] = __builtin_amdgcn_mfma_f32_16x16x32_bf16(
                    ah[tm], bh, acc[tm][tn], 0, 0, 0);
                acc[tm][tn] = __builtin_amdgcn_mfma_f32_16x16x32_bf16(
                    ah[tm], bl, acc[tm][tn], 0, 0, 0);
                acc[tm][tn] = __builtin_amdgcn_mfma_f32_16x16x32_bf16(
                    al[tm], bh, acc[tm][tn], 0, 0, 0);
            }
        }
        __syncthreads();
    }

    #pragma unroll
    for (int tm = 0; tm < 4; tm++) {
        #pragma unroll
        for (int tn = 0; tn < 4; tn++) {
            const int col = col0 + tn * 16 + lr;
            const float b = bias ? bias[col] : 0.0f;
            #pragma unroll
            for (int v = 0; v < 4; v++) {
                const int row = row0 + wave * 64 + tm * 16 + lk * 4 + v;
                C[(size_t)row * N + col] = acc[tm][tn][v] + b;
            }
        }
    }
}

// ---- K1c: action projections (K=16), float4-vectorized -----------------
// blocks 0..2047: ku+vu quads (idx = row*64 + quad); blocks 2048..2303: gamma.
__global__ __launch_bounds__(256) void gemm_act_kernel(
    const float* __restrict__ act, const float* __restrict__ Wku,
    const float* __restrict__ Wvu, const float* __restrict__ Wg,
    float* __restrict__ ku, float* __restrict__ vu, float* __restrict__ bg)
{
    const int bid = blockIdx.x;
    if (bid < ROWS_ * 64 / 256) {
        const int idx = bid * 256 + threadIdx.x;
        const int row = idx >> 6, q = idx & 63, col = q * 4;
        float a[16];
        #pragma unroll
        for (int u = 0; u < 4; u++)
            *(float4*)&a[u*4] = *(const float4*)(act + (size_t)row * NA_ + u * 4);
        float4 accK = {0,0,0,0}, accV = {0,0,0,0};
        #pragma unroll
        for (int kk = 0; kk < NA_; kk++) {
            const float4 wk = *(const float4*)(Wku + (size_t)kk * HID_ + col);
            const float4 wv = *(const float4*)(Wvu + (size_t)kk * HID_ + col);
            accK.x += a[kk]*wk.x; accK.y += a[kk]*wk.y; accK.z += a[kk]*wk.z; accK.w += a[kk]*wk.w;
            accV.x += a[kk]*wv.x; accV.y += a[kk]*wv.y; accV.z += a[kk]*wv.z; accV.w += a[kk]*wv.w;
        }
        *(float4*)(ku + (size_t)row * HID_ + col) = accK;
        *(float4*)(vu + (size_t)row * HID_ + col) = accV;
    } else {
        const int idx = (bid - ROWS_ * 64 / 256) * 256 + threadIdx.x;  // ROWS_*8
        const int row = idx >> 3, c = idx & 7;
        const float* a = act + (size_t)row * NA_;
        float acc = 0.0f;
        #pragma unroll
        for (int kk = 0; kk < NA_; kk++) acc += a[kk] * Wg[kk * H_ + c];
        bg[(size_t)row * H_ + c] = sigmoidf_(acc);
    }
}

// ---- K2: silu + l2norm (per 32-elem head group) for q, k, ku, in place -
__global__ __launch_bounds__(256) void silu_norm_kernel(
    float* __restrict__ q, float* __restrict__ k, float* __restrict__ ku)
{
    const int t = threadIdx.x;
    const int d = t & 31;
    const size_t g = (size_t)blockIdx.x * 8 + (t >> 5);   // head-group id
    const size_t idx = g * 32 + d;
    float* bufs[3] = { q, k, ku };
    #pragma unroll
    for (int a = 0; a < 3; a++) {
        float x = bufs[a][idx];
        float v = x * (1.0f / (1.0f + expf(-x)));
        float ss = v * v;
        ss += __shfl_xor(ss, 1);  ss += __shfl_xor(ss, 2);  ss += __shfl_xor(ss, 4);
        ss += __shfl_xor(ss, 8);  ss += __shfl_xor(ss, 16);
        bufs[a][idx] = v * rsqrtf(ss + 1e-6f);
    }
}

// ---- K3a: per-chunk (cumA, cumB) via rank-1 recurrences ----------------
__global__ __launch_bounds__(256) void scan_pass1(
    const float* __restrict__ kbuf, const float* __restrict__ vbuf,
    const float* __restrict__ kubuf, const float* __restrict__ vubuf,
    const float* __restrict__ bab, const float* __restrict__ gammab,
    const float* __restrict__ mask,
    float* __restrict__ cumA, float* __restrict__ cumB)
{
    const int bh = blockIdx.x;     // 0..31
    const int c  = blockIdx.y;     // 0..NC_-1
    const int b  = bh >> 3, h = bh & 7;
    const int t  = threadIdx.x;
    const int i  = t >> 3;         // state row
    const int j0 = (t & 7) * 4;    // 4 state cols
    __shared__ float lk [T_][32];
    __shared__ float lv [T_][32];
    __shared__ float lku[T_][32];
    __shared__ float lvu[T_][32];
    __shared__ float lsc[T_][4];   // 0:beta 1:alpha*(1-mask) 2:gamma

    float M[4], Cc[4];
    #pragma unroll
    for (int jj = 0; jj < 4; jj++) { M[jj] = (i == j0 + jj) ? 1.0f : 0.0f; Cc[jj] = 0.0f; }

    const float* g0 = (t < 128) ? kbuf  : vbuf;
    const float* g1 = (t < 128) ? kubuf : vubuf;
    const int sr = (t >> 3) & 15, sq = t & 7;

    auto stage = [&](int tile, float4& n0, float4& n1, float& sc) {
        const int row_base = b * S_ + c * CHUNK_ + tile * T_;
        const size_t gb = (size_t)(row_base + sr) * HID_ + h * D_ + sq * 4;
        n0 = *(const float4*)(g0 + gb);
        n1 = *(const float4*)(g1 + gb);
        const int r = t & 15;
        const int rowi = row_base + r;
        if (t < 16)                     sc = sigmoidf_(bab[(size_t)rowi * 64 + h]);
        else if (t >= 64 && t < 80)     sc = sigmoidf_(bab[(size_t)rowi * 64 + 8 + h]) * (1.0f - mask[rowi]);
        else if (t >= 128 && t < 144)   sc = gammab[(size_t)rowi * H_ + h];
    };
    auto commit = [&](float4 n0, float4 n1, float sc) {
        if (t < 128) {
            *(float4*)&lk [sr][sq*4] = n0;
            *(float4*)&lku[sr][sq*4] = n1;
        } else {
            *(float4*)&lv [sr][sq*4] = n0;
            *(float4*)&lvu[sr][sq*4] = n1;
        }
        const int r = t & 15;
        if (t < 16)                     lsc[r][0] = sc;
        else if (t >= 64 && t < 80)     lsc[r][1] = sc;
        else if (t >= 128 && t < 144)   lsc[r][2] = sc;
    };

    float4 p0, p1; float psc = 0.0f;
    stage(0, p0, p1, psc);

    for (int tile = 0; tile < NT_; ++tile) {
        commit(p0, p1, psc);
        __syncthreads();
        float4 n0, n1; float nsc = 0.0f;
        if (tile + 1 < NT_) stage(tile + 1, n0, n1, nsc);

        #pragma unroll
        for (int sl = 0; sl < T_; sl++) {
            const float vi  = lv [sl][i];
            const float vui = lvu[sl][i];
            const float bet = lsc[sl][0];
            const float a   = lsc[sl][1];
            const float bgm = lsc[sl][2];
            float kj[4], kuj[4];
            *(float4*)kj  = *(const float4*)&lk [sl][j0];
            *(float4*)kuj = *(const float4*)&lku[sl][j0];
            float pd = 0.0f, mk = 0.0f, ck = 0.0f;
            #pragma unroll
            for (int jj = 0; jj < 4; jj++) {
                pd += kuj[jj] * kj[jj];
                mk += M[jj]   * kj[jj];
                ck += Cc[jj]  * kj[jj];
            }
            pd += __shfl_xor(pd, 1); pd += __shfl_xor(pd, 2); pd += __shfl_xor(pd, 4);
            mk += __shfl_xor(mk, 1); mk += __shfl_xor(mk, 2); mk += __shfl_xor(mk, 4);
            ck += __shfl_xor(ck, 1); ck += __shfl_xor(ck, 2); ck += __shfl_xor(ck, 4);
            const float abk_m   = a * bet * mk;
            const float ck_coef = bet * vi - a * bet * ck;
            const float wu      = bgm * vui;
            const float bduk    = bet * pd;
            #pragma unroll
            for (int jj = 0; jj < 4; jj++) {
                const float kv = kj[jj];
                const float w  = kuj[jj] - bduk * kv;         // (ku^T @ delta)[j]
                M[jj]  = a * M[jj]  - abk_m   * kv;           // M @ decay
                Cc[jj] = a * Cc[jj] + ck_coef * kv + wu * w;  // C @ decay + update
            }
        }
        __syncthreads();
        p0 = n0; p1 = n1; psc = nsc;
    }
    const size_t ofs = ((size_t)(bh * NC_ + c)) * 1024 + (size_t)i * 32 + j0;
    *(float4*)(cumA + ofs) = make_float4(M[0],  M[1],  M[2],  M[3]);
    *(float4*)(cumB + ofs) = make_float4(Cc[0], Cc[1], Cc[2], Cc[3]);
}

// ---- K3b: sequential chunk composition (256 thr, dbuf LDS, 1 barrier/step)
// Thread (i = t>>3, j0 = (t&7)*4) owns S[i][j0..3]. B stays in registers.
// S and A double-buffered in LDS [32][36] (pad -> conflict-free b128).
// Sstart MAY ALIAS cumA (write of chunk c happens after cumA[c] consumed).
__global__ __launch_bounds__(256) void scan_pass2(
    const float* __restrict__ carry, const float* __restrict__ cumA,
    const float* __restrict__ cumB, float* __restrict__ Sstart,
    float* __restrict__ carry_out)
{
    const int bh = blockIdx.x;
    const int t  = threadIdx.x;
    const int i  = t >> 3;
    const int j0 = (t & 7) * 4;
    __shared__ float Ash[2][32][36];
    __shared__ float Ssh[2][32][36];

    const size_t idx  = (size_t)i * 32 + j0;
    const size_t base = (size_t)bh * NC_ * 1024;

    float4 Sv = *(const float4*)(carry + (size_t)bh * 1024 + idx);
    float4 Areg = *(const float4*)(cumA + base + idx);
    float4 Breg = *(const float4*)(cumB + base + idx);

    *(float4*)&Ssh[0][i][j0] = Sv;
    *(float4*)&Ash[0][i][j0] = Areg;
    __syncthreads();

    int buf = 0;
    for (int c = 0; c < NC_; c++) {
        // emit chunk-start state; prefetch next transform
        *(float4*)(Sstart + base + (size_t)c * 1024 + idx) = Sv;
        float4 Areg2, Breg2;
        if (c + 1 < NC_) {
            Areg2 = *(const float4*)(cumA + base + (size_t)(c + 1) * 1024 + idx);
            Breg2 = *(const float4*)(cumB + base + (size_t)(c + 1) * 1024 + idx);
        }
        // acc = B + S @ A
        float s[32];
        #pragma unroll
        for (int g = 0; g < 8; g++)
            *(float4*)&s[g*4] = *(const float4*)&Ssh[buf][i][g*4];
        float4 acc = Breg;
        #pragma unroll
        for (int m = 0; m < 32; m++) {
            const float4 a4 = *(const float4*)&Ash[buf][m][j0];
            acc.x += s[m] * a4.x; acc.y += s[m] * a4.y;
            acc.z += s[m] * a4.z; acc.w += s[m] * a4.w;
        }
        Sv = acc;
        if (c + 1 < NC_) {
            *(float4*)&Ash[buf ^ 1][i][j0] = Areg2;
            *(float4*)&Ssh[buf ^ 1][i][j0] = Sv;
            Areg = Areg2; Breg = Breg2;
        }
        __syncthreads();
        buf ^= 1;
    }
    *(float4*)(carry_out + (size_t)bh * 1024 + idx) = Sv;
}

// ---- K3c: replay each chunk from Sstart, emit out = S_new . q ----------
__global__ __launch_bounds__(256) void scan_pass3(
    const float* __restrict__ qbuf, const float* __restrict__ kbuf,
    const float* __restrict__ vbuf, const float* __restrict__ kubuf,
    const float* __restrict__ vubuf, const float* __restrict__ bab,
    const float* __restrict__ gammab, const float* __restrict__ mask,
    const float* __restrict__ Sstart, float* __restrict__ outpre)
{
    const int bh = blockIdx.x, c = blockIdx.y;
    const int b  = bh >> 3, h = bh & 7;
    const int t  = threadIdx.x;
    const int i  = t >> 3;
    const int j0 = (t & 7) * 4;
    __shared__ float lk [T_][32];
    __shared__ float lq [T_][32];
    __shared__ float lv [T_][32];
    __shared__ float lku[T_][32];
    __shared__ float lvu[T_][32];
    __shared__ float lsc[T_][4];

    float Sv[4];
    const size_t sofs = ((size_t)(bh * NC_ + c)) * 1024 + (size_t)i * 32 + j0;
    {
        float4 s4 = *(const float4*)(Sstart + sofs);
        Sv[0] = s4.x; Sv[1] = s4.y; Sv[2] = s4.z; Sv[3] = s4.w;
    }

    const float* g0 = (t < 128) ? kbuf  : vbuf;
    const float* g1 = (t < 128) ? kubuf : vubuf;
    const int sr = (t >> 3) & 15, sq = t & 7;

    auto stage = [&](int tile, float4& n0, float4& n1, float4& n2, float& sc) {
        const int row_base = b * S_ + c * CHUNK_ + tile * T_;
        const size_t gb = (size_t)(row_base + sr) * HID_ + h * D_ + sq * 4;
        n0 = *(const float4*)(g0 + gb);
        n1 = *(const float4*)(g1 + gb);
        if (t < 128) n2 = *(const float4*)(qbuf + gb);
        const int r = t & 15;
        const int rowi = row_base + r;
        if (t < 16)                     sc = sigmoidf_(bab[(size_t)rowi * 64 + h]);
        else if (t >= 64 && t < 80)     sc = sigmoidf_(bab[(size_t)rowi * 64 + 8 + h]) * (1.0f - mask[rowi]);
        else if (t >= 128 && t < 144)   sc = gammab[(size_t)rowi * H_ + h];
    };
    auto commit = [&](float4 n0, float4 n1, float4 n2, float sc) {
        if (t < 128) {
            *(float4*)&lk [sr][sq*4] = n0;
            *(float4*)&lku[sr][sq*4] = n1;
            *(float4*)&lq [sr][sq*4] = n2;
        } else {
            *(float4*)&lv [sr][sq*4] = n0;
            *(float4*)&lvu[sr][sq*4] = n1;
        }
        const int r = t & 15;
        if (t < 16)                     lsc[r][0] = sc;
        else if (t >= 64 && t < 80)     lsc[r][1] = sc;
        else if (t >= 128 && t < 144)   lsc[r][2] = sc;
    };

    float4 p0, p1, p2; float psc = 0.0f;
    stage(0, p0, p1, p2, psc);

    for (int tile = 0; tile < NT_; ++tile) {
        commit(p0, p1, p2, psc);
        __syncthreads();
        float4 n0, n1, n2; float nsc = 0.0f;
        if (tile + 1 < NT_) stage(tile + 1, n0, n1, n2, nsc);

        const int row_base = b * S_ + c * CHUNK_ + tile * T_;
        #pragma unroll
        for (int sl = 0; sl < T_; sl++) {
            const float vi  = lv [sl][i];
            const float vui = lvu[sl][i];
            const float bet = lsc[sl][0];
            const float a   = lsc[sl][1];
            const float bgm = lsc[sl][2];
            float kj[4], kuj[4], qj[4];
            *(float4*)kj  = *(const float4*)&lk [sl][j0];
            *(float4*)kuj = *(const float4*)&lku[sl][j0];
            *(float4*)qj  = *(const float4*)&lq [sl][j0];
            float pd = 0.0f, sk = 0.0f;
            #pragma unroll
            for (int jj = 0; jj < 4; jj++) {
                pd += kuj[jj] * kj[jj];
                sk += Sv[jj]  * kj[jj];
            }
            pd += __shfl_xor(pd, 1); pd += __shfl_xor(pd, 2); pd += __shfl_xor(pd, 4);
            sk += __shfl_xor(sk, 1); sk += __shfl_xor(sk, 2); sk += __shfl_xor(sk, 4);
            const float coef_k = bet * vi - a * bet * sk;
            const float wu     = bgm * vui;
            const float bduk   = bet * pd;
            float op = 0.0f;
            #pragma unroll
            for (int jj = 0; jj < 4; jj++) {
                const float kv = kj[jj];
                const float w  = kuj[jj] - bduk * kv;
                Sv[jj] = a * Sv[jj] + coef_k * kv + wu * w;
                op += Sv[jj] * qj[jj];
            }
            op += __shfl_xor(op, 1); op += __shfl_xor(op, 2); op += __shfl_xor(op, 4);
            if ((t & 7) == 0)
                outpre[(size_t)(row_base + sl) * HID_ + h * D_ + i] = op;
        }
        __syncthreads();
        p0 = n0; p1 = n1; p2 = n2; psc = nsc;
    }
}

// ---- K4a: RMS norm + rms_scale -> bf16 hi/lo (one wave per row) --------
__global__ __launch_bounds__(256) void rms_conv_kernel(
    const float* __restrict__ outpre, const float* __restrict__ rms_scale,
    u16* __restrict__ onh, u16* __restrict__ onl)
{
    const int t = threadIdx.x;
    const int lane = t & 63;
    const int row = blockIdx.x * 4 + (t >> 6);
    const float4 v = ((const float4*)(outpre + (size_t)row * HID_))[lane];
    float ss = v.x*v.x + v.y*v.y + v.z*v.z + v.w*v.w;
    ss += __shfl_xor(ss, 1);  ss += __shfl_xor(ss, 2);  ss += __shfl_xor(ss, 4);
    ss += __shfl_xor(ss, 8);  ss += __shfl_xor(ss, 16); ss += __shfl_xor(ss, 32);
    const float rinv = rsqrtf(ss * (1.0f / HID_) + 1e-6f);
    const float4 sc = ((const float4*)rms_scale)[lane];
    ushort4 h, l;
    bfsplit(v.x * rinv * sc.x, h.x, l.x);
    bfsplit(v.y * rinv * sc.y, h.y, l.y);
    bfsplit(v.z * rinv * sc.z, h.z, l.z);
    bfsplit(v.w * rinv * sc.w, h.w, l.w);
    ((ushort4*)(onh + (size_t)row * HID_))[lane] = h;
    ((ushort4*)(onl + (size_t)row * HID_))[lane] = l;
}

// ---- launch ------------------------------------------------------------
extern "C" void kernel_launch(void* const* d_in, const int* in_sizes, int n_in,
                              void* d_out, int out_size, void* d_ws, size_t ws_size,
                              hipStream_t stream)
{
    const float* x      = (const float*)d_in[0];
    const float* action = (const float*)d_in[1];
    const float* mask   = (const float*)d_in[2];
    const float* carry  = (const float*)d_in[3];
    const float* Wq     = (const float*)d_in[4];
    const float* Wk     = (const float*)d_in[5];
    const float* Wv     = (const float*)d_in[6];
    const float* Wbeta  = (const float*)d_in[7];
    const float* Walpha = (const float*)d_in[8];
    const float* Wku    = (const float*)d_in[9];
    const float* Wvu    = (const float*)d_in[10];
    const float* Wgamma = (const float*)d_in[11];
    const float* rms_s  = (const float*)d_in[12];
    const float* Wout   = (const float*)d_in[13];
    const float* bout   = (const float*)d_in[14];

    float* carry_out = (float*)d_out;                       // B*H*D*D = 32768
    float* y         = (float*)d_out + (size_t)BH_ * D_ * D_;

    float* ws = (float*)d_ws;
    float* qb     = ws; ws += (size_t)ROWS_ * HID_;
    float* kb     = ws; ws += (size_t)ROWS_ * HID_;
    float* vb     = ws; ws += (size_t)ROWS_ * HID_;
    float* kub    = ws; ws += (size_t)ROWS_ * HID_;
    float* vub    = ws; ws += (size_t)ROWS_ * HID_;
    float* bab    = ws; ws += (size_t)ROWS_ * 64;          // beta|alpha logits
    float* gammab = ws; ws += (size_t)ROWS_ * H_;
    float* cumA   = ws; ws += (size_t)BH_ * NC_ * D_ * D_; // Sstart aliases this
    float* cumB   = ws; ws += (size_t)BH_ * NC_ * D_ * D_;
    u16* xh       = (u16*)ws;                               // outpre aliases xh/xl
    float* outpre = ws; ws += (size_t)ROWS_ * HID_;
    u16* xl       = (u16*)ws; ws += (size_t)ROWS_ * F_ / 2;
    u16* wth      = (u16*)ws; ws += (size_t)3 * HID_ * F_ / 2;
    u16* wtl      = (u16*)ws; ws += (size_t)3 * HID_ * F_ / 2;
    u16* woth     = (u16*)ws; ws += (size_t)F_ * HID_ / 2;
    u16* wotl     = (u16*)ws; ws += (size_t)F_ * HID_ / 2;
    u16* wbah     = (u16*)ws; ws += (size_t)64 * F_ / 2;   // rows 16-63 unused
    u16* wbal     = (u16*)ws; ws += (size_t)64 * F_ / 2;
    float* Sst    = cumA;
    // onh/onl alias qb (free after scan_pass3; each 4 MB, qb is 8 MB)
    u16* onh = (u16*)qb;
    u16* onl = (u16*)qb + (size_t)ROWS_ * HID_;

    conv_x_kernel<<<dim3(ROWS_ * F_ / 4 / 256), 256, 0, stream>>>(x, xh, xl);
    conv_w_kernel<<<dim3(16, 16, 4), 256, 0, stream>>>(
        Wq, Wk, Wv, Wout, wth, wtl, woth, wotl);
    conv_ba_kernel<<<dim3(16 * F_ / 256), 256, 0, stream>>>(Wbeta, Walpha, wbah, wbal);
    mfma_gemm_kernel<<<dim3(ROWS_/128, HID_/64, 3), 128, 0, stream>>>(
        xh, xl, wth, wtl, qb, F_, HID_, HID_ * F_, ROWS_ * HID_, nullptr);
    mfma_gemm_kernel<<<dim3(ROWS_/128, 1, 1), 128, 0, stream>>>(
        xh, xl, wbah, wbal, bab, F_, 64, 0, 0, nullptr);
    gemm_act_kernel<<<dim3(ROWS_ * 64 / 256 + ROWS_ * 8 / 256), 256, 0, stream>>>(
        action, Wku, Wvu, Wgamma, kub, vub, gammab);
    silu_norm_kernel<<<dim3(ROWS_*H_/8), 256, 0, stream>>>(qb, kb, kub);
    scan_pass1<<<dim3(BH_, NC_), 256, 0, stream>>>(
        kb, vb, kub, vub, bab, gammab, mask, cumA, cumB);
    scan_pass2<<<dim3(BH_), 256, 0, stream>>>(carry, cumA, cumB, Sst, carry_out);
    scan_pass3<<<dim3(BH_, NC_), 256, 0, stream>>>(
        qb, kb, vb, kub, vub, bab, gammab, mask, Sst, outpre);
    rms_conv_kernel<<<dim3(ROWS_/4), 256, 0, stream>>>(outpre, rms_s, onh, onl);
    mfma_gemm_kernel<<<dim3(ROWS_/128, F_/64, 1), 128, 0, stream>>>(
        onh, onl, woth, wotl, y, HID_, F_, 0, 0, bout);
}

// Round 10
// 290.896 us; speedup vs baseline: 1.2408x; 1.0635x over previous
//
#include <hip/hip_runtime.h>
#include <math.h>

// ---- problem constants -------------------------------------------------
constexpr int B_    = 4;
constexpr int S_    = 2048;
constexpr int F_    = 512;     // IN_FEATURES
constexpr int H_    = 8;       // NUM_HEADS
constexpr int D_    = 32;      // HEAD_DIM
constexpr int HID_  = 256;     // H_*D_
constexpr int NA_   = 16;      // NUM_ACTIONS
constexpr int ROWS_ = B_ * S_; // 8192
constexpr int CHUNK_= 32;      // steps per scan chunk
constexpr int NC_   = S_ / CHUNK_;  // 64 chunks
constexpr int T_    = 16;      // timesteps staged per LDS tile
constexpr int NT_   = CHUNK_ / T_;  // 2 tiles per chunk
constexpr int BH_   = B_ * H_;      // 32

typedef __attribute__((ext_vector_type(8))) short short8;
typedef __attribute__((ext_vector_type(4))) float f32x4;
typedef unsigned short u16;

__device__ __forceinline__ float sigmoidf_(float x) { return 1.0f / (1.0f + expf(-x)); }

// fp32 -> bf16 (RNE) and back, plus hi/lo split (a ~= hi + lo, err ~2^-17 rel)
__device__ __forceinline__ u16 f2bf(float f) {
    unsigned u = __float_as_uint(f);
    return (u16)((u + 0x7FFF + ((u >> 16) & 1)) >> 16);
}
__device__ __forceinline__ float bf2f(u16 h) {
    return __uint_as_float(((unsigned)h) << 16);
}
__device__ __forceinline__ void bfsplit(float x, u16& hi, u16& lo) {
    hi = f2bf(x);
    lo = f2bf(x - bf2f(hi));
}

// XOR swizzle within a 64-byte LDS row
__device__ __forceinline__ unsigned swz(unsigned r, unsigned cbyte) {
    return cbyte ^ (((r >> 1) & 3) << 4);
}

// ---- K0a: convert x (f32) -> xh, xl bf16 (row-major 8192x512) ----------
__global__ __launch_bounds__(256) void conv_x_kernel(
    const float* __restrict__ x, u16* __restrict__ xh, u16* __restrict__ xl)
{
    const int idx = blockIdx.x * 256 + threadIdx.x;       // one float4 each
    const float4 v = ((const float4*)x)[idx];
    ushort4 h, l;
    bfsplit(v.x, h.x, l.x); bfsplit(v.y, h.y, l.y);
    bfsplit(v.z, h.z, l.z); bfsplit(v.w, h.w, l.w);
    ((ushort4*)xh)[idx] = h;
    ((ushort4*)xl)[idx] = l;
}

// ---- K0b: transpose + convert weights to [N][K] bf16 hi/lo -------------
__global__ __launch_bounds__(256) void conv_w_kernel(
    const float* __restrict__ Wq, const float* __restrict__ Wk,
    const float* __restrict__ Wv, const float* __restrict__ Wout,
    u16* __restrict__ wth, u16* __restrict__ wtl,
    u16* __restrict__ woth, u16* __restrict__ wotl)
{
    const int z = blockIdx.z;
    const float* src; u16 *dh, *dl; int R, C;
    if (z < 3) {
        src = (z == 0) ? Wq : (z == 1) ? Wk : Wv;
        R = 512; C = 256;
        dh = wth + (size_t)z * 256 * 512; dl = wtl + (size_t)z * 256 * 512;
    } else {
        src = Wout; R = 256; C = 512; dh = woth; dl = wotl;
    }
    const int r0 = blockIdx.x * 32, c0 = blockIdx.y * 32;
    if (r0 >= R || c0 >= C) return;
    __shared__ float tile[32][33];
    const int tx = threadIdx.x & 31, ty = threadIdx.x >> 5;   // 32x8
    #pragma unroll
    for (int i = 0; i < 4; i++)
        tile[ty + i * 8][tx] = src[(size_t)(r0 + ty + i * 8) * C + c0 + tx];
    __syncthreads();
    #pragma unroll
    for (int i = 0; i < 4; i++) {
        const float v = tile[tx][ty + i * 8];
        const size_t o = (size_t)(c0 + ty + i * 8) * R + r0 + tx;
        u16 h, l; bfsplit(v, h, l);
        dh[o] = h; dl[o] = l;
    }
}

// ---- K0c: pack Wbeta|Walpha -> wba [16][512] bf16 hi/lo ----------------
__global__ __launch_bounds__(256) void conv_ba_kernel(
    const float* __restrict__ Wb, const float* __restrict__ Wa,
    u16* __restrict__ wbah, u16* __restrict__ wbal)
{
    const int idx = blockIdx.x * 256 + threadIdx.x;   // 16*512 total
    const int j = idx >> 9, k = idx & 511;
    const float v = (j < 8) ? Wb[(size_t)k * 8 + j] : Wa[(size_t)k * 8 + (j - 8)];
    u16 h, l; bfsplit(v, h, l);
    wbah[(size_t)j * 512 + k] = h;
    wbal[(size_t)j * 512 + k] = l;
}

// ---- K1a: MFMA GEMM  C[8192xN] = A[8192xK] @ Bt[NxK]^T  (bf16x3) -------
__global__ __launch_bounds__(128) void mfma_gemm_kernel(
    const u16* __restrict__ Ah, const u16* __restrict__ Al,
    const u16* __restrict__ Bth, const u16* __restrict__ Btl,
    float* __restrict__ Cbase, int K, int N,
    int btStride, int cStride, const float* __restrict__ bias)
{
    const u16* bh_p = Bth + (size_t)blockIdx.z * btStride;
    const u16* bl_p = Btl + (size_t)blockIdx.z * btStride;
    float* C = Cbase + (size_t)blockIdx.z * cStride;

    __shared__ u16 lAh[128 * 32], lAl[128 * 32];   // 8 KB each
    __shared__ u16 lBh[64 * 32],  lBl[64 * 32];    // 4 KB each

    const int t    = threadIdx.x;
    const int wave = t >> 6;
    const int lane = t & 63;
    const int lr   = lane & 15;        // row/col within fragment
    const int lk   = lane >> 4;        // k-quad (0..3)
    const int row0 = blockIdx.x * 128;
    const int col0 = blockIdx.y * 64;

    f32x4 acc[4][4];
    #pragma unroll
    for (int i = 0; i < 4; i++)
        #pragma unroll
        for (int j = 0; j < 4; j++) acc[i][j] = (f32x4){0.f, 0.f, 0.f, 0.f};

    for (int k0 = 0; k0 < K; k0 += 32) {
        #pragma unroll
        for (int u = 0; u < 4; u++) {
            const int slot = t + u * 128;
            const int r = slot >> 2, cq = slot & 3;
            const size_t g = (size_t)(row0 + r) * K + k0 + cq * 8;
            const unsigned bo = r * 64 + swz(r, cq * 16);
            *(uint4*)((char*)lAh + bo) = *(const uint4*)(Ah + g);
            *(uint4*)((char*)lAl + bo) = *(const uint4*)(Al + g);
        }
        #pragma unroll
        for (int u = 0; u < 2; u++) {
            const int slot = t + u * 128;
            const int r = slot >> 2, cq = slot & 3;
            const size_t g = (size_t)(col0 + r) * K + k0 + cq * 8;
            const unsigned bo = r * 64 + swz(r, cq * 16);
            *(uint4*)((char*)lBh + bo) = *(const uint4*)(bh_p + g);
            *(uint4*)((char*)lBl + bo) = *(const uint4*)(bl_p + g);
        }
        __syncthreads();

        short8 ah[4], al[4];
        #pragma unroll
        for (int tm = 0; tm < 4; tm++) {
            const int r = wave * 64 + tm * 16 + lr;
            const unsigned bo = r * 64 + swz(r, lk * 16);
            ah[tm] = *(const short8*)((const char*)lAh + bo);
            al[tm] = *(const short8*)((const char*)lAl + bo);
        }
        #pragma unroll
        for (int tn = 0; tn < 4; tn++) {
            const int r = tn * 16 + lr;
            const unsigned bo = r * 64 + swz(r, lk * 16);
            const short8 bh = *(const short8*)((const char*)lBh + bo);
            const short8 bl = *(const short8*)((const char*)lBl + bo);
            #pragma unroll
            for (int tm = 0; tm < 4; tm++) {
                acc[tm][tn] = __builtin_amdgcn_mfma_f32_16x16x32_bf16(
                    ah[tm], bh, acc[tm][tn], 0, 0, 0);
                acc[tm][tn] = __builtin_amdgcn_mfma_f32_16x16x32_bf16(
                    ah[tm], bl, acc[tm][tn], 0, 0, 0);
                acc[tm][tn] = __builtin_amdgcn_mfma_f32_16x16x32_bf16(
                    al[tm], bh, acc[tm][tn], 0, 0, 0);
            }
        }
        __syncthreads();
    }

    #pragma unroll
    for (int tm = 0; tm < 4; tm++) {
        #pragma unroll
        for (int tn = 0; tn < 4; tn++) {
            const int col = col0 + tn * 16 + lr;
            const float b = bias ? bias[col] : 0.0f;
            #pragma unroll
            for (int v = 0; v < 4; v++) {
                const int row = row0 + wave * 64 + tm * 16 + lk * 4 + v;
                C[(size_t)row * N + col] = acc[tm][tn][v] + b;
            }
        }
    }
}

// ---- K1c: action projections (K=16), float4-vectorized -----------------
__global__ __launch_bounds__(256) void gemm_act_kernel(
    const float* __restrict__ act, const float* __restrict__ Wku,
    const float* __restrict__ Wvu, const float* __restrict__ Wg,
    float* __restrict__ ku, float* __restrict__ vu, float* __restrict__ bg)
{
    const int bid = blockIdx.x;
    if (bid < ROWS_ * 64 / 256) {
        const int idx = bid * 256 + threadIdx.x;
        const int row = idx >> 6, q = idx & 63, col = q * 4;
        float a[16];
        #pragma unroll
        for (int u = 0; u < 4; u++)
            *(float4*)&a[u*4] = *(const float4*)(act + (size_t)row * NA_ + u * 4);
        float4 accK = {0,0,0,0}, accV = {0,0,0,0};
        #pragma unroll
        for (int kk = 0; kk < NA_; kk++) {
            const float4 wk = *(const float4*)(Wku + (size_t)kk * HID_ + col);
            const float4 wv = *(const float4*)(Wvu + (size_t)kk * HID_ + col);
            accK.x += a[kk]*wk.x; accK.y += a[kk]*wk.y; accK.z += a[kk]*wk.z; accK.w += a[kk]*wk.w;
            accV.x += a[kk]*wv.x; accV.y += a[kk]*wv.y; accV.z += a[kk]*wv.z; accV.w += a[kk]*wv.w;
        }
        *(float4*)(ku + (size_t)row * HID_ + col) = accK;
        *(float4*)(vu + (size_t)row * HID_ + col) = accV;
    } else {
        const int idx = (bid - ROWS_ * 64 / 256) * 256 + threadIdx.x;  // ROWS_*8
        const int row = idx >> 3, c = idx & 7;
        const float* a = act + (size_t)row * NA_;
        float acc = 0.0f;
        #pragma unroll
        for (int kk = 0; kk < NA_; kk++) acc += a[kk] * Wg[kk * H_ + c];
        bg[(size_t)row * H_ + c] = sigmoidf_(acc);
    }
}

// ---- K2: silu + l2norm for q,k,ku + per-(row,head) dot products --------
// dots: duk = k.ku, kq = k.q, kuq = ku.q  (all normalized) -- moves the
// data-only reductions out of the scan's serial loop.
__global__ __launch_bounds__(256) void silu_norm_kernel(
    float* __restrict__ q, float* __restrict__ k, float* __restrict__ ku,
    float* __restrict__ dukb, float* __restrict__ kqb, float* __restrict__ kuqb)
{
    const int t = threadIdx.x;
    const int d = t & 31;
    const size_t g = (size_t)blockIdx.x * 8 + (t >> 5);   // head-group id = row*8+h
    const size_t idx = g * 32 + d;
    const float xq = q[idx], xk = k[idx], xku = ku[idx];
    const float vq = xq * (1.0f / (1.0f + expf(-xq)));
    const float vk = xk * (1.0f / (1.0f + expf(-xk)));
    const float vu = xku * (1.0f / (1.0f + expf(-xku)));
    float sq = vq * vq, sk = vk * vk, su = vu * vu;
    #pragma unroll
    for (int m = 1; m < 32; m <<= 1) {
        sq += __shfl_xor(sq, m); sk += __shfl_xor(sk, m); su += __shfl_xor(su, m);
    }
    const float nq = vq * rsqrtf(sq + 1e-6f);
    const float nk = vk * rsqrtf(sk + 1e-6f);
    const float nu = vu * rsqrtf(su + 1e-6f);
    q[idx] = nq; k[idx] = nk; ku[idx] = nu;
    float duk = nk * nu, kq = nk * nq, kuq = nu * nq;
    #pragma unroll
    for (int m = 1; m < 32; m <<= 1) {
        duk += __shfl_xor(duk, m); kq += __shfl_xor(kq, m); kuq += __shfl_xor(kuq, m);
    }
    if (d == 0)      dukb[g] = duk;
    else if (d == 1) kqb[g]  = kq;
    else if (d == 2) kuqb[g] = kuq;
}

// ---- K3a (fused): per-chunk (cumA,cumB) + per-step (z,y) ---------------
// z_t = P_t q_t,  y_t = C_t q_t  => out_t = Sstart @ z_t + y_t (pass out_asm).
// Uses z_t = a*M_{t-1}.u', y_t = a*C_{t-1}.u' + wu*(kuq - bduk*kq) + bet*kq*v,
// u' = q - bet*kq*k. All 4 state reductions (mk,ck,zq,cq) are independent.
__global__ __launch_bounds__(256) void scan_fused(
    const float* __restrict__ qbuf, const float* __restrict__ kbuf,
    const float* __restrict__ vbuf, const float* __restrict__ kubuf,
    const float* __restrict__ vubuf, const float* __restrict__ bab,
    const float* __restrict__ gammab, const float* __restrict__ dukb,
    const float* __restrict__ kqb, const float* __restrict__ kuqb,
    const float* __restrict__ mask,
    float* __restrict__ cumA, float* __restrict__ cumB,
    float* __restrict__ zbuf, float* __restrict__ ybuf)
{
    const int bh = blockIdx.x;     // 0..31
    const int c  = blockIdx.y;     // 0..NC_-1
    const int b  = bh >> 3, h = bh & 7;
    const int t  = threadIdx.x;
    const int i  = t >> 3;         // state row
    const int j0 = (t & 7) * 4;    // 4 state cols
    __shared__ float lk [T_][32];
    __shared__ float lq [T_][32];
    __shared__ float lv [T_][32];
    __shared__ float lku[T_][32];
    __shared__ float lvu[T_][32];
    __shared__ float lsc[T_][8];   // 0:beta 1:alpha' 2:gamma 3:duk 4:kq 5:kuq

    float M[4], Cc[4];
    #pragma unroll
    for (int jj = 0; jj < 4; jj++) { M[jj] = (i == j0 + jj) ? 1.0f : 0.0f; Cc[jj] = 0.0f; }

    const float* g0 = (t < 128) ? kbuf  : vbuf;
    const float* g1 = (t < 128) ? kubuf : vubuf;
    const int sr = (t >> 3) & 15, sq = t & 7;

    auto stage = [&](int tile, float4& n0, float4& n1, float4& n2, float& sc) {
        const int row_base = b * S_ + c * CHUNK_ + tile * T_;
        const size_t gb = (size_t)(row_base + sr) * HID_ + h * D_ + sq * 4;
        n0 = *(const float4*)(g0 + gb);
        n1 = *(const float4*)(g1 + gb);
        if (t < 128) n2 = *(const float4*)(qbuf + gb);
        const int r = t & 15;
        const int rowi = row_base + r;
        if (t < 16)                     sc = sigmoidf_(bab[(size_t)rowi * 64 + h]);
        else if (t < 32)                sc = dukb[(size_t)rowi * H_ + h];
        else if (t >= 64 && t < 80)     sc = sigmoidf_(bab[(size_t)rowi * 64 + 8 + h]) * (1.0f - mask[rowi]);
        else if (t >= 80 && t < 96)     sc = kqb[(size_t)rowi * H_ + h];
        else if (t >= 128 && t < 144)   sc = gammab[(size_t)rowi * H_ + h];
        else if (t >= 144 && t < 160)   sc = kuqb[(size_t)rowi * H_ + h];
    };
    auto commit = [&](float4 n0, float4 n1, float4 n2, float sc) {
        if (t < 128) {
            *(float4*)&lk [sr][sq*4] = n0;
            *(float4*)&lku[sr][sq*4] = n1;
            *(float4*)&lq [sr][sq*4] = n2;
        } else {
            *(float4*)&lv [sr][sq*4] = n0;
            *(float4*)&lvu[sr][sq*4] = n1;
        }
        const int r = t & 15;
        if (t < 16)                     lsc[r][0] = sc;
        else if (t < 32)                lsc[r][3] = sc;
        else if (t >= 64 && t < 80)     lsc[r][1] = sc;
        else if (t >= 80 && t < 96)     lsc[r][4] = sc;
        else if (t >= 128 && t < 144)   lsc[r][2] = sc;
        else if (t >= 144 && t < 160)   lsc[r][5] = sc;
    };

    float4 p0, p1, p2; float psc = 0.0f;
    stage(0, p0, p1, p2, psc);

    for (int tile = 0; tile < NT_; ++tile) {
        commit(p0, p1, p2, psc);
        __syncthreads();
        float4 n0, n1, n2; float nsc = 0.0f;
        if (tile + 1 < NT_) stage(tile + 1, n0, n1, n2, nsc);

        #pragma unroll
        for (int sl = 0; sl < T_; sl++) {
            const float vi  = lv [sl][i];
            const float vui = lvu[sl][i];
            const float bet = lsc[sl][0];
            const float a   = lsc[sl][1];
            const float bgm = lsc[sl][2];
            const float duk = lsc[sl][3];
            const float kq  = lsc[sl][4];
            const float kuq = lsc[sl][5];
            float kj[4], kuj[4], qj[4];
            *(float4*)kj  = *(const float4*)&lk [sl][j0];
            *(float4*)kuj = *(const float4*)&lku[sl][j0];
            *(float4*)qj  = *(const float4*)&lq [sl][j0];
            const float bduk = bet * duk;
            const float bkq  = bet * kq;
            float uj[4];
            #pragma unroll
            for (int jj = 0; jj < 4; jj++) uj[jj] = qj[jj] - bkq * kj[jj];
            float mk = 0.0f, ck = 0.0f, zq = 0.0f, cq = 0.0f;
            #pragma unroll
            for (int jj = 0; jj < 4; jj++) {
                mk += M[jj]  * kj[jj];
                ck += Cc[jj] * kj[jj];
                zq += M[jj]  * uj[jj];
                cq += Cc[jj] * uj[jj];
            }
            mk += __shfl_xor(mk, 1); ck += __shfl_xor(ck, 1);
            zq += __shfl_xor(zq, 1); cq += __shfl_xor(cq, 1);
            mk += __shfl_xor(mk, 2); ck += __shfl_xor(ck, 2);
            zq += __shfl_xor(zq, 2); cq += __shfl_xor(cq, 2);
            mk += __shfl_xor(mk, 4); ck += __shfl_xor(ck, 4);
            zq += __shfl_xor(zq, 4); cq += __shfl_xor(cq, 4);
            const float am    = a * bet * mk;
            const float wu    = bgm * vui;
            const float kcoef = bet * vi - a * bet * ck - wu * bduk;
            const float zt    = a * zq;
            const float yt    = a * cq + wu * (kuq - bduk * kq) + bet * kq * vi;
            #pragma unroll
            for (int jj = 0; jj < 4; jj++) {
                M[jj]  = a * M[jj]  - am * kj[jj];
                Cc[jj] = a * Cc[jj] + kcoef * kj[jj] + wu * kuj[jj];
            }
            const size_t zofs = (((size_t)(bh * NC_ + c)) * CHUNK_ + tile * T_ + sl) * 32;
            if ((t & 7) == 0)      zbuf[zofs + i] = zt;
            else if ((t & 7) == 1) ybuf[zofs + i] = yt;
        }
        __syncthreads();
        p0 = n0; p1 = n1; p2 = n2; psc = nsc;
    }
    const size_t ofs = ((size_t)(bh * NC_ + c)) * 1024 + (size_t)i * 32 + j0;
    *(float4*)(cumA + ofs) = make_float4(M[0],  M[1],  M[2],  M[3]);
    *(float4*)(cumB + ofs) = make_float4(Cc[0], Cc[1], Cc[2], Cc[3]);
}

// ---- K3b: sequential chunk composition (unchanged from round 5) --------
__global__ __launch_bounds__(256) void scan_pass2(
    const float* __restrict__ carry, const float* __restrict__ cumA,
    const float* __restrict__ cumB, float* __restrict__ Sstart,
    float* __restrict__ carry_out)
{
    const int bh = blockIdx.x;
    const int t  = threadIdx.x;
    const int i  = t >> 3;
    const int j0 = (t & 7) * 4;
    __shared__ float Ash[2][32][36];
    __shared__ float Ssh[2][32][36];

    const size_t idx  = (size_t)i * 32 + j0;
    const size_t base = (size_t)bh * NC_ * 1024;

    float4 Sv = *(const float4*)(carry + (size_t)bh * 1024 + idx);
    float4 Areg = *(const float4*)(cumA + base + idx);
    float4 Breg = *(const float4*)(cumB + base + idx);

    *(float4*)&Ssh[0][i][j0] = Sv;
    *(float4*)&Ash[0][i][j0] = Areg;
    __syncthreads();

    int buf = 0;
    for (int c = 0; c < NC_; c++) {
        *(float4*)(Sstart + base + (size_t)c * 1024 + idx) = Sv;
        float4 Areg2, Breg2;
        if (c + 1 < NC_) {
            Areg2 = *(const float4*)(cumA + base + (size_t)(c + 1) * 1024 + idx);
            Breg2 = *(const float4*)(cumB + base + (size_t)(c + 1) * 1024 + idx);
        }
        float s[32];
        #pragma unroll
        for (int g = 0; g < 8; g++)
            *(float4*)&s[g*4] = *(const float4*)&Ssh[buf][i][g*4];
        float4 acc = Breg;
        #pragma unroll
        for (int m = 0; m < 32; m++) {
            const float4 a4 = *(const float4*)&Ash[buf][m][j0];
            acc.x += s[m] * a4.x; acc.y += s[m] * a4.y;
            acc.z += s[m] * a4.z; acc.w += s[m] * a4.w;
        }
        Sv = acc;
        if (c + 1 < NC_) {
            *(float4*)&Ash[buf ^ 1][i][j0] = Areg2;
            *(float4*)&Ssh[buf ^ 1][i][j0] = Sv;
            Areg = Areg2; Breg = Breg2;
        }
        __syncthreads();
        buf ^= 1;
    }
    *(float4*)(carry_out + (size_t)bh * 1024 + idx) = Sv;
}

// ---- K3c: out assembly  out[t] = Sstart @ z_t + y_t  (fully parallel) --
__global__ __launch_bounds__(256) void out_asm_kernel(
    const float* __restrict__ Sstart, const float* __restrict__ zbuf,
    const float* __restrict__ ybuf, float* __restrict__ outpre)
{
    const int bh = blockIdx.x, c = blockIdx.y;
    const int b  = bh >> 3, h = bh & 7;
    const int t  = threadIdx.x;
    __shared__ float Ssh[32][33];
    __shared__ float Zsh[32][33];
    const size_t ofs = ((size_t)(bh * NC_ + c)) * 1024;   // 32 steps x 32
    {
        const float4 s4 = *(const float4*)(Sstart + ofs + t * 4);
        *(float4*)&Ssh[t >> 3][(t & 7) * 4] = s4;
        const float4 z4 = *(const float4*)(zbuf + ofs + t * 4);
        *(float4*)&Zsh[t >> 3][(t & 7) * 4] = z4;
    }
    __syncthreads();
    const int tt = t >> 3;          // step 0..31
    const int iq = (t & 7) * 4;     // 4 output rows
    float4 acc = *(const float4*)(ybuf + ofs + (size_t)tt * 32 + iq);
    #pragma unroll
    for (int j = 0; j < 32; j++) {
        const float zj = Zsh[tt][j];
        acc.x += Ssh[iq + 0][j] * zj;
        acc.y += Ssh[iq + 1][j] * zj;
        acc.z += Ssh[iq + 2][j] * zj;
        acc.w += Ssh[iq + 3][j] * zj;
    }
    const int s = c * CHUNK_ + tt;
    *(float4*)(outpre + ((size_t)(b * S_ + s)) * HID_ + h * D_ + iq) = acc;
}

// ---- K4a: RMS norm + rms_scale -> bf16 hi/lo (one wave per row) --------
__global__ __launch_bounds__(256) void rms_conv_kernel(
    const float* __restrict__ outpre, const float* __restrict__ rms_scale,
    u16* __restrict__ onh, u16* __restrict__ onl)
{
    const int t = threadIdx.x;
    const int lane = t & 63;
    const int row = blockIdx.x * 4 + (t >> 6);
    const float4 v = ((const float4*)(outpre + (size_t)row * HID_))[lane];
    float ss = v.x*v.x + v.y*v.y + v.z*v.z + v.w*v.w;
    ss += __shfl_xor(ss, 1);  ss += __shfl_xor(ss, 2);  ss += __shfl_xor(ss, 4);
    ss += __shfl_xor(ss, 8);  ss += __shfl_xor(ss, 16); ss += __shfl_xor(ss, 32);
    const float rinv = rsqrtf(ss * (1.0f / HID_) + 1e-6f);
    const float4 sc = ((const float4*)rms_scale)[lane];
    ushort4 h, l;
    bfsplit(v.x * rinv * sc.x, h.x, l.x);
    bfsplit(v.y * rinv * sc.y, h.y, l.y);
    bfsplit(v.z * rinv * sc.z, h.z, l.z);
    bfsplit(v.w * rinv * sc.w, h.w, l.w);
    ((ushort4*)(onh + (size_t)row * HID_))[lane] = h;
    ((ushort4*)(onl + (size_t)row * HID_))[lane] = l;
}

// ---- launch ------------------------------------------------------------
extern "C" void kernel_launch(void* const* d_in, const int* in_sizes, int n_in,
                              void* d_out, int out_size, void* d_ws, size_t ws_size,
                              hipStream_t stream)
{
    const float* x      = (const float*)d_in[0];
    const float* action = (const float*)d_in[1];
    const float* mask   = (const float*)d_in[2];
    const float* carry  = (const float*)d_in[3];
    const float* Wq     = (const float*)d_in[4];
    const float* Wk     = (const float*)d_in[5];
    const float* Wv     = (const float*)d_in[6];
    const float* Wbeta  = (const float*)d_in[7];
    const float* Walpha = (const float*)d_in[8];
    const float* Wku    = (const float*)d_in[9];
    const float* Wvu    = (const float*)d_in[10];
    const float* Wgamma = (const float*)d_in[11];
    const float* rms_s  = (const float*)d_in[12];
    const float* Wout   = (const float*)d_in[13];
    const float* bout   = (const float*)d_in[14];

    float* carry_out = (float*)d_out;                       // B*H*D*D = 32768
    float* y         = (float*)d_out + (size_t)BH_ * D_ * D_;

    float* ws = (float*)d_ws;
    float* qb     = ws; ws += (size_t)ROWS_ * HID_;
    float* kb     = ws; ws += (size_t)ROWS_ * HID_;
    float* vb     = ws; ws += (size_t)ROWS_ * HID_;
    float* kub    = ws; ws += (size_t)ROWS_ * HID_;
    float* vub    = ws; ws += (size_t)ROWS_ * HID_;
    float* bab    = ws; ws += (size_t)ROWS_ * 64;          // beta|alpha logits
    float* gammab = ws; ws += (size_t)ROWS_ * H_;
    float* dukb   = ws; ws += (size_t)ROWS_ * H_;
    float* kqb    = ws; ws += (size_t)ROWS_ * H_;
    float* kuqb   = ws; ws += (size_t)ROWS_ * H_;
    float* cumA   = ws; ws += (size_t)BH_ * NC_ * D_ * D_; // Sstart aliases this
    float* cumB   = ws; ws += (size_t)BH_ * NC_ * D_ * D_;
    float* zbuf   = ws; ws += (size_t)BH_ * S_ * D_;       // 2M floats
    float* ybuf   = ws; ws += (size_t)BH_ * S_ * D_;
    u16* xh       = (u16*)ws;                               // outpre aliases xh/xl
    float* outpre = ws; ws += (size_t)ROWS_ * HID_;
    u16* xl       = (u16*)ws; ws += (size_t)ROWS_ * F_ / 2;
    u16* wth      = (u16*)ws; ws += (size_t)3 * HID_ * F_ / 2;
    u16* wtl      = (u16*)ws; ws += (size_t)3 * HID_ * F_ / 2;
    u16* woth     = (u16*)ws; ws += (size_t)F_ * HID_ / 2;
    u16* wotl     = (u16*)ws; ws += (size_t)F_ * HID_ / 2;
    u16* wbah     = (u16*)ws; ws += (size_t)64 * F_ / 2;   // rows 16-63 unused
    u16* wbal     = (u16*)ws; ws += (size_t)64 * F_ / 2;
    float* Sst    = cumA;
    // onh/onl alias qb (free after scan; each 4 MB, qb is 8 MB)
    u16* onh = (u16*)qb;
    u16* onl = (u16*)qb + (size_t)ROWS_ * HID_;

    conv_x_kernel<<<dim3(ROWS_ * F_ / 4 / 256), 256, 0, stream>>>(x, xh, xl);
    conv_w_kernel<<<dim3(16, 16, 4), 256, 0, stream>>>(
        Wq, Wk, Wv, Wout, wth, wtl, woth, wotl);
    conv_ba_kernel<<<dim3(16 * F_ / 256), 256, 0, stream>>>(Wbeta, Walpha, wbah, wbal);
    mfma_gemm_kernel<<<dim3(ROWS_/128, HID_/64, 3), 128, 0, stream>>>(
        xh, xl, wth, wtl, qb, F_, HID_, HID_ * F_, ROWS_ * HID_, nullptr);
    mfma_gemm_kernel<<<dim3(ROWS_/128, 1, 1), 128, 0, stream>>>(
        xh, xl, wbah, wbal, bab, F_, 64, 0, 0, nullptr);
    gemm_act_kernel<<<dim3(ROWS_ * 64 / 256 + ROWS_ * 8 / 256), 256, 0, stream>>>(
        action, Wku, Wvu, Wgamma, kub, vub, gammab);
    silu_norm_kernel<<<dim3(ROWS_*H_/8), 256, 0, stream>>>(
        qb, kb, kub, dukb, kqb, kuqb);
    scan_fused<<<dim3(BH_, NC_), 256, 0, stream>>>(
        qb, kb, vb, kub, vub, bab, gammab, dukb, kqb, kuqb, mask,
        cumA, cumB, zbuf, ybuf);
    scan_pass2<<<dim3(BH_), 256, 0, stream>>>(carry, cumA, cumB, Sst, carry_out);
    out_asm_kernel<<<dim3(BH_, NC_), 256, 0, stream>>>(Sst, zbuf, ybuf, outpre);
    rms_conv_kernel<<<dim3(ROWS_/4), 256, 0, stream>>>(outpre, rms_s, onh, onl);
    mfma_gemm_kernel<<<dim3(ROWS_/128, F_/64, 1), 128, 0, stream>>>(
        onh, onl, woth, wotl, y, HID_, F_, 0, 0, bout);
}

// Round 11
// 264.511 us; speedup vs baseline: 1.3646x; 1.0997x over previous
//
#include <hip/hip_runtime.h>
#include <math.h>

// ---- problem constants -------------------------------------------------
constexpr int B_    = 4;
constexpr int S_    = 2048;
constexpr int F_    = 512;     // IN_FEATURES
constexpr int H_    = 8;       // NUM_HEADS
constexpr int D_    = 32;      // HEAD_DIM
constexpr int HID_  = 256;     // H_*D_
constexpr int NA_   = 16;      // NUM_ACTIONS
constexpr int ROWS_ = B_ * S_; // 8192
constexpr int CHUNK_= 32;      // steps per scan chunk
constexpr int NC_   = S_ / CHUNK_;  // 64 chunks
constexpr int T_    = 16;      // timesteps staged per LDS tile
constexpr int NT_   = CHUNK_ / T_;  // 2 tiles per chunk
constexpr int BH_   = B_ * H_;      // 32

typedef __attribute__((ext_vector_type(8))) short short8;
typedef __attribute__((ext_vector_type(4))) float f32x4;
typedef unsigned short u16;

__device__ __forceinline__ float sigmoidf_(float x) { return 1.0f / (1.0f + expf(-x)); }

// fp32 -> bf16 (RNE) and back, plus hi/lo split (a ~= hi + lo, err ~2^-17 rel)
__device__ __forceinline__ u16 f2bf(float f) {
    unsigned u = __float_as_uint(f);
    return (u16)((u + 0x7FFF + ((u >> 16) & 1)) >> 16);
}
__device__ __forceinline__ float bf2f(u16 h) {
    return __uint_as_float(((unsigned)h) << 16);
}
__device__ __forceinline__ void bfsplit(float x, u16& hi, u16& lo) {
    hi = f2bf(x);
    lo = f2bf(x - bf2f(hi));
}

// XOR swizzle within a 64-byte LDS row
__device__ __forceinline__ unsigned swz(unsigned r, unsigned cbyte) {
    return cbyte ^ (((r >> 1) & 3) << 4);
}

// 8-lane sum-reduce entirely on the VALU pipe via DPP (no LDS traffic):
// xor1 = quad_perm[1,0,3,2] (0xB1), xor2 = quad_perm[2,3,0,1] (0x4E),
// xor7 = row_half_mirror (0x141) -- pairs complementary 4-groups.
#define DPPADD(v, ctrl) \
    v += __int_as_float(__builtin_amdgcn_mov_dpp(__float_as_int(v), ctrl, 0xF, 0xF, false))

// ---- K0a: convert x (f32) -> xh, xl bf16 (row-major 8192x512) ----------
__global__ __launch_bounds__(256) void conv_x_kernel(
    const float* __restrict__ x, u16* __restrict__ xh, u16* __restrict__ xl)
{
    const int idx = blockIdx.x * 256 + threadIdx.x;       // one float4 each
    const float4 v = ((const float4*)x)[idx];
    ushort4 h, l;
    bfsplit(v.x, h.x, l.x); bfsplit(v.y, h.y, l.y);
    bfsplit(v.z, h.z, l.z); bfsplit(v.w, h.w, l.w);
    ((ushort4*)xh)[idx] = h;
    ((ushort4*)xl)[idx] = l;
}

// ---- K0b: transpose + convert weights to [N][K] bf16 hi/lo -------------
__global__ __launch_bounds__(256) void conv_w_kernel(
    const float* __restrict__ Wq, const float* __restrict__ Wk,
    const float* __restrict__ Wv, const float* __restrict__ Wout,
    u16* __restrict__ wth, u16* __restrict__ wtl,
    u16* __restrict__ woth, u16* __restrict__ wotl)
{
    const int z = blockIdx.z;
    const float* src; u16 *dh, *dl; int R, C;
    if (z < 3) {
        src = (z == 0) ? Wq : (z == 1) ? Wk : Wv;
        R = 512; C = 256;
        dh = wth + (size_t)z * 256 * 512; dl = wtl + (size_t)z * 256 * 512;
    } else {
        src = Wout; R = 256; C = 512; dh = woth; dl = wotl;
    }
    const int r0 = blockIdx.x * 32, c0 = blockIdx.y * 32;
    if (r0 >= R || c0 >= C) return;
    __shared__ float tile[32][33];
    const int tx = threadIdx.x & 31, ty = threadIdx.x >> 5;   // 32x8
    #pragma unroll
    for (int i = 0; i < 4; i++)
        tile[ty + i * 8][tx] = src[(size_t)(r0 + ty + i * 8) * C + c0 + tx];
    __syncthreads();
    #pragma unroll
    for (int i = 0; i < 4; i++) {
        const float v = tile[tx][ty + i * 8];
        const size_t o = (size_t)(c0 + ty + i * 8) * R + r0 + tx;
        u16 h, l; bfsplit(v, h, l);
        dh[o] = h; dl[o] = l;
    }
}

// ---- K0c: pack Wbeta|Walpha -> wba [16][512] bf16 hi/lo ----------------
__global__ __launch_bounds__(256) void conv_ba_kernel(
    const float* __restrict__ Wb, const float* __restrict__ Wa,
    u16* __restrict__ wbah, u16* __restrict__ wbal)
{
    const int idx = blockIdx.x * 256 + threadIdx.x;   // 16*512 total
    const int j = idx >> 9, k = idx & 511;
    const float v = (j < 8) ? Wb[(size_t)k * 8 + j] : Wa[(size_t)k * 8 + (j - 8)];
    u16 h, l; bfsplit(v, h, l);
    wbah[(size_t)j * 512 + k] = h;
    wbal[(size_t)j * 512 + k] = l;
}

// ---- K1a: fused qkv + beta/alpha MFMA GEMM (K=512, bf16x3) -------------
// blockIdx.y = 0..11: qkv (z = y>>2, col-tile = y&3, N=256);
// blockIdx.y = 12:    beta/alpha slice (wba [64][512], N=64; rows 16-63 of
//                     wba are junk -> outputs land in unread bab columns).
__global__ __launch_bounds__(128) void mfma_qkvba_kernel(
    const u16* __restrict__ Ah, const u16* __restrict__ Al,
    const u16* __restrict__ wth, const u16* __restrict__ wtl,
    const u16* __restrict__ wbah, const u16* __restrict__ wbal,
    float* __restrict__ qkv, float* __restrict__ bab)
{
    const int m = blockIdx.y;
    const u16 *bh_p, *bl_p; float* C; int N, col0;
    if (m < 12) {
        const int z = m >> 2; col0 = (m & 3) * 64;
        bh_p = wth + (size_t)z * 256 * 512;
        bl_p = wtl + (size_t)z * 256 * 512;
        C = qkv + (size_t)z * ROWS_ * HID_; N = HID_;
    } else {
        col0 = 0; bh_p = wbah; bl_p = wbal; C = bab; N = 64;
    }

    __shared__ u16 lAh[128 * 32], lAl[128 * 32];   // 8 KB each
    __shared__ u16 lBh[64 * 32],  lBl[64 * 32];    // 4 KB each

    const int t    = threadIdx.x;
    const int wave = t >> 6;
    const int lane = t & 63;
    const int lr   = lane & 15;
    const int lk   = lane >> 4;
    const int row0 = blockIdx.x * 128;

    f32x4 acc[4][4];
    #pragma unroll
    for (int i = 0; i < 4; i++)
        #pragma unroll
        for (int j = 0; j < 4; j++) acc[i][j] = (f32x4){0.f, 0.f, 0.f, 0.f};

    for (int k0 = 0; k0 < F_; k0 += 32) {
        #pragma unroll
        for (int u = 0; u < 4; u++) {
            const int slot = t + u * 128;
            const int r = slot >> 2, cq = slot & 3;
            const size_t g = (size_t)(row0 + r) * F_ + k0 + cq * 8;
            const unsigned bo = r * 64 + swz(r, cq * 16);
            *(uint4*)((char*)lAh + bo) = *(const uint4*)(Ah + g);
            *(uint4*)((char*)lAl + bo) = *(const uint4*)(Al + g);
        }
        #pragma unroll
        for (int u = 0; u < 2; u++) {
            const int slot = t + u * 128;
            const int r = slot >> 2, cq = slot & 3;
            const size_t g = (size_t)(col0 + r) * F_ + k0 + cq * 8;
            const unsigned bo = r * 64 + swz(r, cq * 16);
            *(uint4*)((char*)lBh + bo) = *(const uint4*)(bh_p + g);
            *(uint4*)((char*)lBl + bo) = *(const uint4*)(bl_p + g);
        }
        __syncthreads();

        short8 ah[4], al[4];
        #pragma unroll
        for (int tm = 0; tm < 4; tm++) {
            const int r = wave * 64 + tm * 16 + lr;
            const unsigned bo = r * 64 + swz(r, lk * 16);
            ah[tm] = *(const short8*)((const char*)lAh + bo);
            al[tm] = *(const short8*)((const char*)lAl + bo);
        }
        #pragma unroll
        for (int tn = 0; tn < 4; tn++) {
            const int r = tn * 16 + lr;
            const unsigned bo = r * 64 + swz(r, lk * 16);
            const short8 bh = *(const short8*)((const char*)lBh + bo);
            const short8 bl = *(const short8*)((const char*)lBl + bo);
            #pragma unroll
            for (int tm = 0; tm < 4; tm++) {
                acc[tm][tn] = __builtin_amdgcn_mfma_f32_16x16x32_bf16(
                    ah[tm], bh, acc[tm][tn], 0, 0, 0);
                acc[tm][tn] = __builtin_amdgcn_mfma_f32_16x16x32_bf16(
                    ah[tm], bl, acc[tm][tn], 0, 0, 0);
                acc[tm][tn] = __builtin_amdgcn_mfma_f32_16x16x32_bf16(
                    al[tm], bh, acc[tm][tn], 0, 0, 0);
            }
        }
        __syncthreads();
    }

    #pragma unroll
    for (int tm = 0; tm < 4; tm++) {
        #pragma unroll
        for (int tn = 0; tn < 4; tn++) {
            const int col = col0 + tn * 16 + lr;
            #pragma unroll
            for (int v = 0; v < 4; v++) {
                const int row = row0 + wave * 64 + tm * 16 + lk * 4 + v;
                C[(size_t)row * N + col] = acc[tm][tn][v];
            }
        }
    }
}

// ---- K1b: generic MFMA GEMM (used for the out-projection) --------------
__global__ __launch_bounds__(128) void mfma_gemm_kernel(
    const u16* __restrict__ Ah, const u16* __restrict__ Al,
    const u16* __restrict__ Bth, const u16* __restrict__ Btl,
    float* __restrict__ C, int K, int N, const float* __restrict__ bias)
{
    __shared__ u16 lAh[128 * 32], lAl[128 * 32];
    __shared__ u16 lBh[64 * 32],  lBl[64 * 32];

    const int t    = threadIdx.x;
    const int wave = t >> 6;
    const int lane = t & 63;
    const int lr   = lane & 15;
    const int lk   = lane >> 4;
    const int row0 = blockIdx.x * 128;
    const int col0 = blockIdx.y * 64;

    f32x4 acc[4][4];
    #pragma unroll
    for (int i = 0; i < 4; i++)
        #pragma unroll
        for (int j = 0; j < 4; j++) acc[i][j] = (f32x4){0.f, 0.f, 0.f, 0.f};

    for (int k0 = 0; k0 < K; k0 += 32) {
        #pragma unroll
        for (int u = 0; u < 4; u++) {
            const int slot = t + u * 128;
            const int r = slot >> 2, cq = slot & 3;
            const size_t g = (size_t)(row0 + r) * K + k0 + cq * 8;
            const unsigned bo = r * 64 + swz(r, cq * 16);
            *(uint4*)((char*)lAh + bo) = *(const uint4*)(Ah + g);
            *(uint4*)((char*)lAl + bo) = *(const uint4*)(Al + g);
        }
        #pragma unroll
        for (int u = 0; u < 2; u++) {
            const int slot = t + u * 128;
            const int r = slot >> 2, cq = slot & 3;
            const size_t g = (size_t)(col0 + r) * K + k0 + cq * 8;
            const unsigned bo = r * 64 + swz(r, cq * 16);
            *(uint4*)((char*)lBh + bo) = *(const uint4*)(Bth + g);
            *(uint4*)((char*)lBl + bo) = *(const uint4*)(Btl + g);
        }
        __syncthreads();

        short8 ah[4], al[4];
        #pragma unroll
        for (int tm = 0; tm < 4; tm++) {
            const int r = wave * 64 + tm * 16 + lr;
            const unsigned bo = r * 64 + swz(r, lk * 16);
            ah[tm] = *(const short8*)((const char*)lAh + bo);
            al[tm] = *(const short8*)((const char*)lAl + bo);
        }
        #pragma unroll
        for (int tn = 0; tn < 4; tn++) {
            const int r = tn * 16 + lr;
            const unsigned bo = r * 64 + swz(r, lk * 16);
            const short8 bh = *(const short8*)((const char*)lBh + bo);
            const short8 bl = *(const short8*)((const char*)lBl + bo);
            #pragma unroll
            for (int tm = 0; tm < 4; tm++) {
                acc[tm][tn] = __builtin_amdgcn_mfma_f32_16x16x32_bf16(
                    ah[tm], bh, acc[tm][tn], 0, 0, 0);
                acc[tm][tn] = __builtin_amdgcn_mfma_f32_16x16x32_bf16(
                    ah[tm], bl, acc[tm][tn], 0, 0, 0);
                acc[tm][tn] = __builtin_amdgcn_mfma_f32_16x16x32_bf16(
                    al[tm], bh, acc[tm][tn], 0, 0, 0);
            }
        }
        __syncthreads();
    }

    #pragma unroll
    for (int tm = 0; tm < 4; tm++) {
        #pragma unroll
        for (int tn = 0; tn < 4; tn++) {
            const int col = col0 + tn * 16 + lr;
            const float b = bias ? bias[col] : 0.0f;
            #pragma unroll
            for (int v = 0; v < 4; v++) {
                const int row = row0 + wave * 64 + tm * 16 + lk * 4 + v;
                C[(size_t)row * N + col] = acc[tm][tn][v] + b;
            }
        }
    }
}

// ---- K1c: action projections (K=16), float4-vectorized -----------------
__global__ __launch_bounds__(256) void gemm_act_kernel(
    const float* __restrict__ act, const float* __restrict__ Wku,
    const float* __restrict__ Wvu, const float* __restrict__ Wg,
    float* __restrict__ ku, float* __restrict__ vu, float* __restrict__ bg)
{
    const int bid = blockIdx.x;
    if (bid < ROWS_ * 64 / 256) {
        const int idx = bid * 256 + threadIdx.x;
        const int row = idx >> 6, q = idx & 63, col = q * 4;
        float a[16];
        #pragma unroll
        for (int u = 0; u < 4; u++)
            *(float4*)&a[u*4] = *(const float4*)(act + (size_t)row * NA_ + u * 4);
        float4 accK = {0,0,0,0}, accV = {0,0,0,0};
        #pragma unroll
        for (int kk = 0; kk < NA_; kk++) {
            const float4 wk = *(const float4*)(Wku + (size_t)kk * HID_ + col);
            const float4 wv = *(const float4*)(Wvu + (size_t)kk * HID_ + col);
            accK.x += a[kk]*wk.x; accK.y += a[kk]*wk.y; accK.z += a[kk]*wk.z; accK.w += a[kk]*wk.w;
            accV.x += a[kk]*wv.x; accV.y += a[kk]*wv.y; accV.z += a[kk]*wv.z; accV.w += a[kk]*wv.w;
        }
        *(float4*)(ku + (size_t)row * HID_ + col) = accK;
        *(float4*)(vu + (size_t)row * HID_ + col) = accV;
    } else {
        const int idx = (bid - ROWS_ * 64 / 256) * 256 + threadIdx.x;  // ROWS_*8
        const int row = idx >> 3, c = idx & 7;
        const float* a = act + (size_t)row * NA_;
        float acc = 0.0f;
        #pragma unroll
        for (int kk = 0; kk < NA_; kk++) acc += a[kk] * Wg[kk * H_ + c];
        bg[(size_t)row * H_ + c] = sigmoidf_(acc);
    }
}

// ---- K2: silu + l2norm for q,k,ku + per-(row,head) dot products --------
__global__ __launch_bounds__(256) void silu_norm_kernel(
    float* __restrict__ q, float* __restrict__ k, float* __restrict__ ku,
    float* __restrict__ dukb, float* __restrict__ kqb, float* __restrict__ kuqb)
{
    const int t = threadIdx.x;
    const int d = t & 31;
    const size_t g = (size_t)blockIdx.x * 8 + (t >> 5);   // head-group id = row*8+h
    const size_t idx = g * 32 + d;
    const float xq = q[idx], xk = k[idx], xku = ku[idx];
    const float vq = xq * (1.0f / (1.0f + expf(-xq)));
    const float vk = xk * (1.0f / (1.0f + expf(-xk)));
    const float vu = xku * (1.0f / (1.0f + expf(-xku)));
    float sq = vq * vq, sk = vk * vk, su = vu * vu;
    #pragma unroll
    for (int m = 1; m < 32; m <<= 1) {
        sq += __shfl_xor(sq, m); sk += __shfl_xor(sk, m); su += __shfl_xor(su, m);
    }
    const float nq = vq * rsqrtf(sq + 1e-6f);
    const float nk = vk * rsqrtf(sk + 1e-6f);
    const float nu = vu * rsqrtf(su + 1e-6f);
    q[idx] = nq; k[idx] = nk; ku[idx] = nu;
    float duk = nk * nu, kq = nk * nq, kuq = nu * nq;
    #pragma unroll
    for (int m = 1; m < 32; m <<= 1) {
        duk += __shfl_xor(duk, m); kq += __shfl_xor(kq, m); kuq += __shfl_xor(kuq, m);
    }
    if (d == 0)      dukb[g] = duk;
    else if (d == 1) kqb[g]  = kq;
    else if (d == 2) kuqb[g] = kuq;
}

// ---- K3a (fused): per-chunk (cumA,cumB) + per-step (z,y) ---------------
// z_t = a*(mq - bkq*mk), y_t = a*(cq - bkq*ck) + wu*(kuq-bduk*kq) + bet*kq*v.
// 4 reductions {mk,ck,mq,cq} done with DPP (VALU pipe, no LDS traffic).
__global__ __launch_bounds__(256) void scan_fused(
    const float* __restrict__ qbuf, const float* __restrict__ kbuf,
    const float* __restrict__ vbuf, const float* __restrict__ kubuf,
    const float* __restrict__ vubuf, const float* __restrict__ bab,
    const float* __restrict__ gammab, const float* __restrict__ dukb,
    const float* __restrict__ kqb, const float* __restrict__ kuqb,
    const float* __restrict__ mask,
    float* __restrict__ cumA, float* __restrict__ cumB,
    float* __restrict__ zbuf, float* __restrict__ ybuf)
{
    const int bh = blockIdx.x;     // 0..31
    const int c  = blockIdx.y;     // 0..NC_-1
    const int b  = bh >> 3, h = bh & 7;
    const int t  = threadIdx.x;
    const int i  = t >> 3;         // state row
    const int j0 = (t & 7) * 4;    // 4 state cols
    __shared__ float lk [T_][32];
    __shared__ float lq [T_][32];
    __shared__ float lv [T_][32];
    __shared__ float lku[T_][32];
    __shared__ float lvu[T_][32];
    __shared__ float lsc[T_][8];   // 0:beta 1:alpha' 2:gamma 3:duk 4:kq 5:kuq

    float M[4], Cc[4];
    #pragma unroll
    for (int jj = 0; jj < 4; jj++) { M[jj] = (i == j0 + jj) ? 1.0f : 0.0f; Cc[jj] = 0.0f; }

    const float* g0 = (t < 128) ? kbuf  : vbuf;
    const float* g1 = (t < 128) ? kubuf : vubuf;
    const int sr = (t >> 3) & 15, sq = t & 7;

    auto stage = [&](int tile, float4& n0, float4& n1, float4& n2, float& sc) {
        const int row_base = b * S_ + c * CHUNK_ + tile * T_;
        const size_t gb = (size_t)(row_base + sr) * HID_ + h * D_ + sq * 4;
        n0 = *(const float4*)(g0 + gb);
        n1 = *(const float4*)(g1 + gb);
        if (t < 128) n2 = *(const float4*)(qbuf + gb);
        const int r = t & 15;
        const int rowi = row_base + r;
        if (t < 16)                     sc = sigmoidf_(bab[(size_t)rowi * 64 + h]);
        else if (t < 32)                sc = dukb[(size_t)rowi * H_ + h];
        else if (t >= 64 && t < 80)     sc = sigmoidf_(bab[(size_t)rowi * 64 + 8 + h]) * (1.0f - mask[rowi]);
        else if (t >= 80 && t < 96)     sc = kqb[(size_t)rowi * H_ + h];
        else if (t >= 128 && t < 144)   sc = gammab[(size_t)rowi * H_ + h];
        else if (t >= 144 && t < 160)   sc = kuqb[(size_t)rowi * H_ + h];
    };
    auto commit = [&](float4 n0, float4 n1, float4 n2, float sc) {
        if (t < 128) {
            *(float4*)&lk [sr][sq*4] = n0;
            *(float4*)&lku[sr][sq*4] = n1;
            *(float4*)&lq [sr][sq*4] = n2;
        } else {
            *(float4*)&lv [sr][sq*4] = n0;
            *(float4*)&lvu[sr][sq*4] = n1;
        }
        const int r = t & 15;
        if (t < 16)                     lsc[r][0] = sc;
        else if (t < 32)                lsc[r][3] = sc;
        else if (t >= 64 && t < 80)     lsc[r][1] = sc;
        else if (t >= 80 && t < 96)     lsc[r][4] = sc;
        else if (t >= 128 && t < 144)   lsc[r][2] = sc;
        else if (t >= 144 && t < 160)   lsc[r][5] = sc;
    };

    float4 p0, p1, p2; float psc = 0.0f;
    stage(0, p0, p1, p2, psc);

    for (int tile = 0; tile < NT_; ++tile) {
        commit(p0, p1, p2, psc);
        __syncthreads();
        float4 n0, n1, n2; float nsc = 0.0f;
        if (tile + 1 < NT_) stage(tile + 1, n0, n1, n2, nsc);

        #pragma unroll
        for (int sl = 0; sl < T_; sl++) {
            const float vi  = lv [sl][i];
            const float vui = lvu[sl][i];
            const float bet = lsc[sl][0];
            const float a   = lsc[sl][1];
            const float bgm = lsc[sl][2];
            const float duk = lsc[sl][3];
            const float kq  = lsc[sl][4];
            const float kuq = lsc[sl][5];
            float kj[4], kuj[4], qj[4];
            *(float4*)kj  = *(const float4*)&lk [sl][j0];
            *(float4*)kuj = *(const float4*)&lku[sl][j0];
            *(float4*)qj  = *(const float4*)&lq [sl][j0];
            float mk = 0.0f, ck = 0.0f, mq = 0.0f, cq = 0.0f;
            #pragma unroll
            for (int jj = 0; jj < 4; jj++) {
                mk += M[jj]  * kj[jj];
                ck += Cc[jj] * kj[jj];
                mq += M[jj]  * qj[jj];
                cq += Cc[jj] * qj[jj];
            }
            // 8-lane butterfly on the VALU pipe (DPP), interleaved for ILP
            DPPADD(mk, 0xB1);  DPPADD(ck, 0xB1);  DPPADD(mq, 0xB1);  DPPADD(cq, 0xB1);
            DPPADD(mk, 0x4E);  DPPADD(ck, 0x4E);  DPPADD(mq, 0x4E);  DPPADD(cq, 0x4E);
            DPPADD(mk, 0x141); DPPADD(ck, 0x141); DPPADD(mq, 0x141); DPPADD(cq, 0x141);
            const float bduk  = bet * duk;
            const float bkq   = bet * kq;
            const float am    = a * bet * mk;
            const float wu    = bgm * vui;
            const float kcoef = bet * vi - a * bet * ck - wu * bduk;
            const float zt    = a * (mq - bkq * mk);
            const float yt    = a * (cq - bkq * ck) + wu * (kuq - bduk * kq) + bet * kq * vi;
            #pragma unroll
            for (int jj = 0; jj < 4; jj++) {
                M[jj]  = a * M[jj]  - am * kj[jj];
                Cc[jj] = a * Cc[jj] + kcoef * kj[jj] + wu * kuj[jj];
            }
            const size_t zofs = (((size_t)(bh * NC_ + c)) * CHUNK_ + tile * T_ + sl) * 32;
            if ((t & 7) == 0)      zbuf[zofs + i] = zt;
            else if ((t & 7) == 1) ybuf[zofs + i] = yt;
        }
        __syncthreads();
        p0 = n0; p1 = n1; p2 = n2; psc = nsc;
    }
    const size_t ofs = ((size_t)(bh * NC_ + c)) * 1024 + (size_t)i * 32 + j0;
    *(float4*)(cumA + ofs) = make_float4(M[0],  M[1],  M[2],  M[3]);
    *(float4*)(cumB + ofs) = make_float4(Cc[0], Cc[1], Cc[2], Cc[3]);
}

// ---- K3b: sequential chunk composition (unchanged) ---------------------
__global__ __launch_bounds__(256) void scan_pass2(
    const float* __restrict__ carry, const float* __restrict__ cumA,
    const float* __restrict__ cumB, float* __restrict__ Sstart,
    float* __restrict__ carry_out)
{
    const int bh = blockIdx.x;
    const int t  = threadIdx.x;
    const int i  = t >> 3;
    const int j0 = (t & 7) * 4;
    __shared__ float Ash[2][32][36];
    __shared__ float Ssh[2][32][36];

    const size_t idx  = (size_t)i * 32 + j0;
    const size_t base = (size_t)bh * NC_ * 1024;

    float4 Sv = *(const float4*)(carry + (size_t)bh * 1024 + idx);
    float4 Areg = *(const float4*)(cumA + base + idx);
    float4 Breg = *(const float4*)(cumB + base + idx);

    *(float4*)&Ssh[0][i][j0] = Sv;
    *(float4*)&Ash[0][i][j0] = Areg;
    __syncthreads();

    int buf = 0;
    for (int c = 0; c < NC_; c++) {
        *(float4*)(Sstart + base + (size_t)c * 1024 + idx) = Sv;
        float4 Areg2, Breg2;
        if (c + 1 < NC_) {
            Areg2 = *(const float4*)(cumA + base + (size_t)(c + 1) * 1024 + idx);
            Breg2 = *(const float4*)(cumB + base + (size_t)(c + 1) * 1024 + idx);
        }
        float s[32];
        #pragma unroll
        for (int g = 0; g < 8; g++)
            *(float4*)&s[g*4] = *(const float4*)&Ssh[buf][i][g*4];
        float4 acc = Breg;
        #pragma unroll
        for (int m = 0; m < 32; m++) {
            const float4 a4 = *(const float4*)&Ash[buf][m][j0];
            acc.x += s[m] * a4.x; acc.y += s[m] * a4.y;
            acc.z += s[m] * a4.z; acc.w += s[m] * a4.w;
        }
        Sv = acc;
        if (c + 1 < NC_) {
            *(float4*)&Ash[buf ^ 1][i][j0] = Areg2;
            *(float4*)&Ssh[buf ^ 1][i][j0] = Sv;
            Areg = Areg2; Breg = Breg2;
        }
        __syncthreads();
        buf ^= 1;
    }
    *(float4*)(carry_out + (size_t)bh * 1024 + idx) = Sv;
}

// ---- K3c: out assembly  out[t] = Sstart @ z_t + y_t  (fully parallel) --
__global__ __launch_bounds__(256) void out_asm_kernel(
    const float* __restrict__ Sstart, const float* __restrict__ zbuf,
    const float* __restrict__ ybuf, float* __restrict__ outpre)
{
    const int bh = blockIdx.x, c = blockIdx.y;
    const int b  = bh >> 3, h = bh & 7;
    const int t  = threadIdx.x;
    __shared__ float Ssh[32][33];
    __shared__ float Zsh[32][33];
    const size_t ofs = ((size_t)(bh * NC_ + c)) * 1024;   // 32 steps x 32
    {
        const float4 s4 = *(const float4*)(Sstart + ofs + t * 4);
        *(float4*)&Ssh[t >> 3][(t & 7) * 4] = s4;
        const float4 z4 = *(const float4*)(zbuf + ofs + t * 4);
        *(float4*)&Zsh[t >> 3][(t & 7) * 4] = z4;
    }
    __syncthreads();
    const int tt = t >> 3;          // step 0..31
    const int iq = (t & 7) * 4;     // 4 output rows
    float4 acc = *(const float4*)(ybuf + ofs + (size_t)tt * 32 + iq);
    #pragma unroll
    for (int j = 0; j < 32; j++) {
        const float zj = Zsh[tt][j];
        acc.x += Ssh[iq + 0][j] * zj;
        acc.y += Ssh[iq + 1][j] * zj;
        acc.z += Ssh[iq + 2][j] * zj;
        acc.w += Ssh[iq + 3][j] * zj;
    }
    const int s = c * CHUNK_ + tt;
    *(float4*)(outpre + ((size_t)(b * S_ + s)) * HID_ + h * D_ + iq) = acc;
}

// ---- K4a: RMS norm + rms_scale -> bf16 hi/lo (one wave per row) --------
__global__ __launch_bounds__(256) void rms_conv_kernel(
    const float* __restrict__ outpre, const float* __restrict__ rms_scale,
    u16* __restrict__ onh, u16* __restrict__ onl)
{
    const int t = threadIdx.x;
    const int lane = t & 63;
    const int row = blockIdx.x * 4 + (t >> 6);
    const float4 v = ((const float4*)(outpre + (size_t)row * HID_))[lane];
    float ss = v.x*v.x + v.y*v.y + v.z*v.z + v.w*v.w;
    ss += __shfl_xor(ss, 1);  ss += __shfl_xor(ss, 2);  ss += __shfl_xor(ss, 4);
    ss += __shfl_xor(ss, 8);  ss += __shfl_xor(ss, 16); ss += __shfl_xor(ss, 32);
    const float rinv = rsqrtf(ss * (1.0f / HID_) + 1e-6f);
    const float4 sc = ((const float4*)rms_scale)[lane];
    ushort4 h, l;
    bfsplit(v.x * rinv * sc.x, h.x, l.x);
    bfsplit(v.y * rinv * sc.y, h.y, l.y);
    bfsplit(v.z * rinv * sc.z, h.z, l.z);
    bfsplit(v.w * rinv * sc.w, h.w, l.w);
    ((ushort4*)(onh + (size_t)row * HID_))[lane] = h;
    ((ushort4*)(onl + (size_t)row * HID_))[lane] = l;
}

// ---- launch ------------------------------------------------------------
extern "C" void kernel_launch(void* const* d_in, const int* in_sizes, int n_in,
                              void* d_out, int out_size, void* d_ws, size_t ws_size,
                              hipStream_t stream)
{
    const float* x      = (const float*)d_in[0];
    const float* action = (const float*)d_in[1];
    const float* mask   = (const float*)d_in[2];
    const float* carry  = (const float*)d_in[3];
    const float* Wq     = (const float*)d_in[4];
    const float* Wk     = (const float*)d_in[5];
    const float* Wv     = (const float*)d_in[6];
    const float* Wbeta  = (const float*)d_in[7];
    const float* Walpha = (const float*)d_in[8];
    const float* Wku    = (const float*)d_in[9];
    const float* Wvu    = (const float*)d_in[10];
    const float* Wgamma = (const float*)d_in[11];
    const float* rms_s  = (const float*)d_in[12];
    const float* Wout   = (const float*)d_in[13];
    const float* bout   = (const float*)d_in[14];

    float* carry_out = (float*)d_out;                       // B*H*D*D = 32768
    float* y         = (float*)d_out + (size_t)BH_ * D_ * D_;

    float* ws = (float*)d_ws;
    float* qb     = ws; ws += (size_t)ROWS_ * HID_;
    float* kb     = ws; ws += (size_t)ROWS_ * HID_;
    float* vb     = ws; ws += (size_t)ROWS_ * HID_;
    float* kub    = ws; ws += (size_t)ROWS_ * HID_;
    float* vub    = ws; ws += (size_t)ROWS_ * HID_;
    float* bab    = ws; ws += (size_t)ROWS_ * 64;          // beta|alpha logits
    float* gammab = ws; ws += (size_t)ROWS_ * H_;
    float* dukb   = ws; ws += (size_t)ROWS_ * H_;
    float* kqb    = ws; ws += (size_t)ROWS_ * H_;
    float* kuqb   = ws; ws += (size_t)ROWS_ * H_;
    float* cumA   = ws; ws += (size_t)BH_ * NC_ * D_ * D_; // Sstart aliases this
    float* cumB   = ws; ws += (size_t)BH_ * NC_ * D_ * D_;
    float* zbuf   = ws; ws += (size_t)BH_ * S_ * D_;       // 2M floats
    float* ybuf   = ws; ws += (size_t)BH_ * S_ * D_;
    u16* xh       = (u16*)ws;                               // outpre aliases xh/xl
    float* outpre = ws; ws += (size_t)ROWS_ * HID_;
    u16* xl       = (u16*)ws; ws += (size_t)ROWS_ * F_ / 2;
    u16* wth      = (u16*)ws; ws += (size_t)3 * HID_ * F_ / 2;
    u16* wtl      = (u16*)ws; ws += (size_t)3 * HID_ * F_ / 2;
    u16* woth     = (u16*)ws; ws += (size_t)F_ * HID_ / 2;
    u16* wotl     = (u16*)ws; ws += (size_t)F_ * HID_ / 2;
    u16* wbah     = (u16*)ws; ws += (size_t)64 * F_ / 2;   // rows 16-63 junk
    u16* wbal     = (u16*)ws; ws += (size_t)64 * F_ / 2;
    float* Sst    = cumA;
    // onh/onl alias qb (free after scan; each 4 MB, qb is 8 MB)
    u16* onh = (u16*)qb;
    u16* onl = (u16*)qb + (size_t)ROWS_ * HID_;

    conv_x_kernel<<<dim3(ROWS_ * F_ / 4 / 256), 256, 0, stream>>>(x, xh, xl);
    conv_w_kernel<<<dim3(16, 16, 4), 256, 0, stream>>>(
        Wq, Wk, Wv, Wout, wth, wtl, woth, wotl);
    conv_ba_kernel<<<dim3(16 * F_ / 256), 256, 0, stream>>>(Wbeta, Walpha, wbah, wbal);
    mfma_qkvba_kernel<<<dim3(ROWS_/128, 13), 128, 0, stream>>>(
        xh, xl, wth, wtl, wbah, wbal, qb, bab);
    gemm_act_kernel<<<dim3(ROWS_ * 64 / 256 + ROWS_ * 8 / 256), 256, 0, stream>>>(
        action, Wku, Wvu, Wgamma, kub, vub, gammab);
    silu_norm_kernel<<<dim3(ROWS_*H_/8), 256, 0, stream>>>(
        qb, kb, kub, dukb, kqb, kuqb);
    scan_fused<<<dim3(BH_, NC_), 256, 0, stream>>>(
        qb, kb, vb, kub, vub, bab, gammab, dukb, kqb, kuqb, mask,
        cumA, cumB, zbuf, ybuf);
    scan_pass2<<<dim3(BH_), 256, 0, stream>>>(carry, cumA, cumB, Sst, carry_out);
    out_asm_kernel<<<dim3(BH_, NC_), 256, 0, stream>>>(Sst, zbuf, ybuf, outpre);
    rms_conv_kernel<<<dim3(ROWS_/4), 256, 0, stream>>>(outpre, rms_s, onh, onl);
    mfma_gemm_kernel<<<dim3(ROWS_/128, F_/64), 128, 0, stream>>>(
        onh, onl, woth, wotl, y, HID_, F_, bout);
}